// Round 1
// baseline (797.856 us; speedup 1.0000x reference)
//
#include <hip/hip_runtime.h>
#include <math.h>

#define BB 2
#define TT 2304
#define CIN 256
#define C4 64
#define NHEADS 4
#define DHV 64
#define HHH 48
#define WWW 48
#define EPSV 1e-5f

// workspace layout (float offsets)
#define WS_IDENT 0            // [BB][CIN][TT]            1179648
#define WS_RT    1179648      // [4][BB][TT][C4]          1179648
#define WS_DWT   2359296      // [C4][BB*TT] col-major     294912
#define WS_YS    2654208      // [3][BB][C4][TT]           884736
#define WS_QKV   3538944      // [3][4][BB][NHEADS][TT][DHV]
#define QKV_SZ   4718592
#define WS_OCAT  17694720     // [BB][TT][1024]           4718592

// ---------------------------------------------------------------------------
// Generic 64x64-tile fp32 GEMM, A [M][K] row-major (or [K][M] col-major for
// MODE 1), W [N][K] row-major (torch Linear layout). 256 thr, 4x4/thread.
// MODE 0: conv_in + BN1 -> identity (ch-major) + r_t scale0 (tok-major)
// MODE 1: pointwise + BN2 -> r_t[scale] + ys_ch[scale-1]
// MODE 2: q/k/v projection (blockIdx.z selects W), head-split store
// MODE 3: output projection -> d_out
// ---------------------------------------------------------------------------
template<int MODE>
__global__ __launch_bounds__(256) void gemm64(
    const float* __restrict__ A,
    const float* __restrict__ W0, const float* __restrict__ W1, const float* __restrict__ W2,
    float* __restrict__ out, float* __restrict__ out2,
    const float* __restrict__ bg, const float* __restrict__ bb,
    const float* __restrict__ bm, const float* __restrict__ bv,
    int Kdim, int scale_s)
{
    __shared__ __align__(16) float As[16][68];
    __shared__ __align__(16) float Ws[16][68];
    const int tid = threadIdx.x;
    const int m0 = blockIdx.x * 64;
    const int n0 = blockIdx.y * 64;
    const float* W = W0;
    float* ob = out;
    if (MODE == 2) {
        if (blockIdx.z == 1) { W = W1; ob = out + (size_t)QKV_SZ; }
        else if (blockIdx.z == 2) { W = W2; ob = out + 2 * (size_t)QKV_SZ; }
    }
    const int tm = tid & 15, tn = tid >> 4;
    float acc[4][4] = {};
    for (int k0 = 0; k0 < Kdim; k0 += 16) {
        __syncthreads();
        if (MODE == 1) {
            const int kk = tid >> 4, mc = tid & 15;
            float4 a4 = *(const float4*)&A[(size_t)(k0 + kk) * (BB * TT) + m0 + mc * 4];
            *(float4*)&As[kk][mc * 4] = a4;
        } else {
            const int lr = tid >> 2, lc = tid & 3;
            float4 a4 = *(const float4*)&A[(size_t)(m0 + lr) * Kdim + k0 + lc * 4];
            As[lc * 4 + 0][lr] = a4.x; As[lc * 4 + 1][lr] = a4.y;
            As[lc * 4 + 2][lr] = a4.z; As[lc * 4 + 3][lr] = a4.w;
        }
        {
            const int lr = tid >> 2, lc = tid & 3;
            float4 w4 = *(const float4*)&W[(size_t)(n0 + lr) * Kdim + k0 + lc * 4];
            Ws[lc * 4 + 0][lr] = w4.x; Ws[lc * 4 + 1][lr] = w4.y;
            Ws[lc * 4 + 2][lr] = w4.z; Ws[lc * 4 + 3][lr] = w4.w;
        }
        __syncthreads();
        #pragma unroll
        for (int kk = 0; kk < 16; ++kk) {
            float4 af = *(const float4*)&As[kk][tm * 4];
            float4 wf = *(const float4*)&Ws[kk][tn * 4];
            float av[4] = {af.x, af.y, af.z, af.w};
            float wv[4] = {wf.x, wf.y, wf.z, wf.w};
            #pragma unroll
            for (int i = 0; i < 4; ++i)
                #pragma unroll
                for (int j = 0; j < 4; ++j)
                    acc[i][j] = fmaf(av[i], wv[j], acc[i][j]);
        }
    }

    if (MODE == 0) {
        #pragma unroll
        for (int j = 0; j < 4; ++j) {
            const int o = n0 + tn * 4 + j;
            const float inv = bg[o] * rsqrtf(bv[o] + EPSV);
            const float bet = bb[o] - bm[o] * inv;
            #pragma unroll
            for (int i = 0; i < 4; ++i) {
                const int m = m0 + tm * 4 + i;
                const int b = m / TT, t = m % TT;
                const float val = acc[i][j] * inv + bet;
                out[((size_t)(b * CIN + o)) * TT + t] = val;
                if (o < C4) out2[((size_t)(b * TT + t)) * C4 + o] = val;
            }
        }
    } else if (MODE == 1) {
        #pragma unroll
        for (int j = 0; j < 4; ++j) {
            const int o = n0 + tn * 4 + j;
            const float inv = bg[o] * rsqrtf(bv[o] + EPSV);
            const float bet = bb[o] - bm[o] * inv;
            #pragma unroll
            for (int i = 0; i < 4; ++i) {
                const int m = m0 + tm * 4 + i;
                const int b = m / TT, t = m % TT;
                const float val = acc[i][j] * inv + bet;
                out[(((size_t)scale_s * BB + b) * TT + t) * C4 + o] = val;
                out2[(((size_t)(scale_s - 1) * BB + b) * C4 + o) * TT + t] = val;
            }
        }
    } else if (MODE == 2) {
        #pragma unroll
        for (int i = 0; i < 4; ++i) {
            const int m = m0 + tm * 4 + i;
            const int s = m / (BB * TT);
            const int rem = m % (BB * TT);
            const int b = rem / TT, t = rem % TT;
            const int o = n0 + tn * 4;
            const int h = o >> 6, d = o & 63;
            float4 v4 = make_float4(acc[i][0], acc[i][1], acc[i][2], acc[i][3]);
            *(float4*)&ob[((((size_t)s * BB + b) * NHEADS + h) * TT + t) * DHV + d] = v4;
        }
    } else {
        #pragma unroll
        for (int i = 0; i < 4; ++i) {
            const int m = m0 + tm * 4 + i;
            float4 v4 = make_float4(acc[i][0], acc[i][1], acc[i][2], acc[i][3]);
            *(float4*)&out[(size_t)m * CIN + n0 + tn * 4] = v4;
        }
    }
}

// ---------------------------------------------------------------------------
// Depthwise 3x3 SAME, input = identity scale-slice (+ previous ys), output
// col-major [C4][BB*TT] so the pointwise GEMM's LDS staging is coalesced.
// ---------------------------------------------------------------------------
__global__ __launch_bounds__(256) void dw3x3(
    const float* __restrict__ ident, const float* __restrict__ ysprev,
    const float* __restrict__ dww, float* __restrict__ dwt, int s)
{
    const int g = blockIdx.x * 256 + threadIdx.x;
    const int t = g % TT;
    const int c = (g / TT) & (C4 - 1);
    const int b = g / (TT * C4);
    const int h = t / WWW, w = t % WWW;
    const float* p1 = ident + ((size_t)(b * CIN + s * C4 + c)) * TT;
    const float* p2 = ysprev ? (ysprev + ((size_t)(b * C4 + c)) * TT) : nullptr;
    float acc = 0.f;
    #pragma unroll
    for (int kh = 0; kh < 3; ++kh) {
        const int hh2 = h + kh - 1;
        if (hh2 < 0 || hh2 >= HHH) continue;
        #pragma unroll
        for (int kw = 0; kw < 3; ++kw) {
            const int ww2 = w + kw - 1;
            if (ww2 < 0 || ww2 >= WWW) continue;
            const int t2 = hh2 * WWW + ww2;
            float v = p1[t2];
            if (p2) v += p2[t2];
            acc = fmaf(v, dww[c * 9 + kh * 3 + kw], acc);
        }
    }
    dwt[(size_t)c * (BB * TT) + b * TT + t] = acc;
}

// ---------------------------------------------------------------------------
// fp32 flash attention. One block (4 waves) = 64 q-rows of one (s,b,h).
// K-tiles of 64. Per thread: 4q x 4k S-tile / 4q x 4d O-tile.
// Rows map to stride-4 lane groups -> softmax reductions are intra-wave
// __shfl_xor(4/8/16/32). qT/PT accesses are wave-local by construction.
// LDS rows padded to 68 floats (272 B): 16B-aligned b128 + no 2^n conflicts.
// ---------------------------------------------------------------------------
__global__ __launch_bounds__(256) void attn_fp32(
    const float* __restrict__ qg, const float* __restrict__ kg,
    const float* __restrict__ vg, float* __restrict__ ocat)
{
    __shared__ __align__(16) float qT[64][68];   // [d][qrow]
    __shared__ __align__(16) float kv[64][68];   // kT [d][kcol], then V [krow][d]
    __shared__ __align__(16) float PT[64][68];   // [kcol][qrow]
    const int tid = threadIdx.x;
    const int combo = blockIdx.y;                // (s*BB+b)*NHEADS+h
    const int qbase = blockIdx.x * 64;
    const float* Q = qg + (size_t)combo * TT * DHV;
    const float* K = kg + (size_t)combo * TT * DHV;
    const float* V = vg + (size_t)combo * TT * DHV;
    const int wv = tid >> 6;
    const int lane = tid & 63;
    const int qr0 = wv * 16 + (lane & 3) * 4;    // block-local q row base
    const int kc0 = (lane >> 2) * 4;             // k col base == d col base

    {   // stage Q transposed (wave-local rows)
        const int r = tid >> 2;
        #pragma unroll
        for (int rep = 0; rep < 4; ++rep) {
            const int c0 = ((tid & 3) + rep * 4) * 4;
            float4 qv = *(const float4*)&Q[(size_t)(qbase + r) * DHV + c0];
            qT[c0 + 0][r] = qv.x; qT[c0 + 1][r] = qv.y;
            qT[c0 + 2][r] = qv.z; qT[c0 + 3][r] = qv.w;
        }
    }
    float o[4][4] = {};
    float mrun[4], lrun[4];
    #pragma unroll
    for (int i = 0; i < 4; ++i) { mrun[i] = -1e30f; lrun[i] = 0.f; }

    for (int kt = 0; kt < TT; kt += 64) {
        __syncthreads();                          // protect kv from prior PV
        {   // stage K transposed
            const int r = tid >> 2;
            #pragma unroll
            for (int rep = 0; rep < 4; ++rep) {
                const int c0 = ((tid & 3) + rep * 4) * 4;
                float4 kq = *(const float4*)&K[(size_t)(kt + r) * DHV + c0];
                kv[c0 + 0][r] = kq.x; kv[c0 + 1][r] = kq.y;
                kv[c0 + 2][r] = kq.z; kv[c0 + 3][r] = kq.w;
            }
        }
        __syncthreads();
        float sv[4][4] = {};
        #pragma unroll 8
        for (int c = 0; c < 64; ++c) {
            float4 qf = *(const float4*)&qT[c][qr0];
            float4 kf = *(const float4*)&kv[c][kc0];
            float qa[4] = {qf.x, qf.y, qf.z, qf.w};
            float ka[4] = {kf.x, kf.y, kf.z, kf.w};
            #pragma unroll
            for (int i = 0; i < 4; ++i)
                #pragma unroll
                for (int j = 0; j < 4; ++j)
                    sv[i][j] = fmaf(qa[i], ka[j], sv[i][j]);
        }
        // online softmax (rows live in stride-4 lane groups)
        #pragma unroll
        for (int i = 0; i < 4; ++i) {
            float mx = fmaxf(fmaxf(sv[i][0], sv[i][1]), fmaxf(sv[i][2], sv[i][3]));
            mx = fmaxf(mx, __shfl_xor(mx, 4));
            mx = fmaxf(mx, __shfl_xor(mx, 8));
            mx = fmaxf(mx, __shfl_xor(mx, 16));
            mx = fmaxf(mx, __shfl_xor(mx, 32));
            const float mnew = fmaxf(mrun[i], mx);
            const float corr = __expf(mrun[i] - mnew);
            float ps = 0.f;
            #pragma unroll
            for (int j = 0; j < 4; ++j) { sv[i][j] = __expf(sv[i][j] - mnew); ps += sv[i][j]; }
            ps += __shfl_xor(ps, 4);
            ps += __shfl_xor(ps, 8);
            ps += __shfl_xor(ps, 16);
            ps += __shfl_xor(ps, 32);
            lrun[i] = lrun[i] * corr + ps;
            mrun[i] = mnew;
            #pragma unroll
            for (int j = 0; j < 4; ++j) o[i][j] *= corr;
        }
        // write P transposed (wave-local columns)
        #pragma unroll
        for (int j = 0; j < 4; ++j) {
            float4 p4 = make_float4(sv[0][j], sv[1][j], sv[2][j], sv[3][j]);
            *(float4*)&PT[kc0 + j][qr0] = p4;
        }
        __syncthreads();                          // everyone done with kT
        {   // stage V (natural layout) into kv
            const int r = tid >> 2;
            #pragma unroll
            for (int rep = 0; rep < 4; ++rep) {
                const int c0 = ((tid & 3) + rep * 4) * 4;
                float4 vv = *(const float4*)&V[(size_t)(kt + r) * DHV + c0];
                *(float4*)&kv[r][c0] = vv;
            }
        }
        __syncthreads();
        #pragma unroll 8
        for (int kc = 0; kc < 64; ++kc) {
            float4 pf = *(const float4*)&PT[kc][qr0];
            float4 vf = *(const float4*)&kv[kc][kc0];
            float pa[4] = {pf.x, pf.y, pf.z, pf.w};
            float va[4] = {vf.x, vf.y, vf.z, vf.w};
            #pragma unroll
            for (int i = 0; i < 4; ++i)
                #pragma unroll
                for (int j = 0; j < 4; ++j)
                    o[i][j] = fmaf(pa[i], va[j], o[i][j]);
        }
    }
    const int s_ = combo >> 3, b_ = (combo >> 2) & 1, h_ = combo & 3;
    #pragma unroll
    for (int i = 0; i < 4; ++i) {
        const float invl = 1.f / lrun[i];
        const int trow = qbase + qr0 + i;
        float4 ov = make_float4(o[i][0] * invl, o[i][1] * invl,
                                o[i][2] * invl, o[i][3] * invl);
        *(float4*)&ocat[((size_t)(b_ * TT + trow)) * 1024 + s_ * 256 + h_ * 64 + kc0] = ov;
    }
}

// ---------------------------------------------------------------------------
extern "C" void kernel_launch(void* const* d_in, const int* in_sizes, int n_in,
                              void* d_out, int out_size, void* d_ws, size_t ws_size,
                              hipStream_t stream)
{
    const float* x    = (const float*)d_in[0];
    const float* wci  = (const float*)d_in[1];
    const float* b1g  = (const float*)d_in[2];
    const float* b1b  = (const float*)d_in[3];
    const float* b1m  = (const float*)d_in[4];
    const float* b1v  = (const float*)d_in[5];
    const float* dww  = (const float*)d_in[6];
    const float* pww  = (const float*)d_in[7];
    const float* b2g  = (const float*)d_in[8];
    const float* b2b  = (const float*)d_in[9];
    const float* b2m  = (const float*)d_in[10];
    const float* b2v  = (const float*)d_in[11];
    const float* Wq   = (const float*)d_in[12];
    const float* Wk   = (const float*)d_in[13];
    const float* Wv   = (const float*)d_in[14];
    const float* Wout = (const float*)d_in[15];

    float* ws    = (float*)d_ws;
    float* ident = ws + WS_IDENT;
    float* rt    = ws + WS_RT;
    float* dwt   = ws + WS_DWT;
    float* ysch  = ws + WS_YS;
    float* qkv   = ws + WS_QKV;
    float* ocat  = ws + WS_OCAT;
    float* outp  = (float*)d_out;

    // 1) conv_in (1x1) + BN1
    gemm64<0><<<dim3(BB * TT / 64, CIN / 64), 256, 0, stream>>>(
        x, wci, nullptr, nullptr, ident, rt, b1g, b1b, b1m, b1v, CIN, 0);

    // 2) Res2Net chain: dw3x3 -> pw 1x1 + BN2, scales 1..3 (sequential)
    for (int s = 1; s <= 3; ++s) {
        const float* yp = (s == 1) ? nullptr : (ysch + (size_t)(s - 2) * BB * C4 * TT);
        dw3x3<<<dim3(BB * C4 * TT / 256), 256, 0, stream>>>(ident, yp, dww, dwt, s);
        gemm64<1><<<dim3(BB * TT / 64, 1), 256, 0, stream>>>(
            dwt, pww, nullptr, nullptr, rt, ysch, b2g, b2b, b2m, b2v, C4, s);
    }

    // 3) q/k/v projections (head-split store)
    gemm64<2><<<dim3(4 * BB * TT / 64, CIN / 64, 3), 256, 0, stream>>>(
        rt, Wq, Wk, Wv, qkv, nullptr, nullptr, nullptr, nullptr, nullptr, C4, 0);

    // 4) flash attention -> concatenated o [B][T][1024]
    attn_fp32<<<dim3(TT / 64, 32), 256, 0, stream>>>(
        qkv, qkv + (size_t)QKV_SZ, qkv + 2 * (size_t)QKV_SZ, ocat);

    // 5) output projection -> d_out
    gemm64<3><<<dim3(BB * TT / 64, CIN / 64), 256, 0, stream>>>(
        ocat, Wout, nullptr, nullptr, outp, nullptr, nullptr, nullptr, nullptr, nullptr,
        4 * CIN, 0);
}

// Round 7
// 414.408 us; speedup vs baseline: 1.9253x; 1.9253x over previous
//
#include <hip/hip_runtime.h>
#include <math.h>

#define BB 2
#define TT 2304
#define CIN 256
#define C4 64
#define NHEADS 4
#define DHV 64
#define HHH 48
#define WWW 48
#define EPSV 1e-5f
#define LOG2E 1.4426950408889634f

using f16x8 = __attribute__((ext_vector_type(8))) _Float16;
using f32x4 = __attribute__((ext_vector_type(4))) float;

// pack two f32 -> one u32 of two f16 (RTZ), type-safe via bit_cast
__device__ __forceinline__ unsigned pk2(float a, float b) {
    return __builtin_bit_cast(unsigned, __builtin_amdgcn_cvt_pkrtz(a, b));
}

// workspace layout (byte offsets)
#define WSB_IDENT 0u          // [BB][CIN][TT] f32      4718592
#define WSB_RT    4718592u    // [4][BB][TT][C4] f32    4718592
#define WSB_DWT   9437184u    // [C4][BB*TT] f32        1179648
#define WSB_YS    10616832u   // [3][BB][C4][TT] f32    3538944
#define WSB_QH    14155776u   // [32][TT][64] f16       9437184  (pre-scaled by log2e)
#define WSB_KH    23592960u   // [32][TT][64] f16       9437184
#define WSB_VT    33030144u   // [32][64][TT] f16       9437184  (V transposed)
#define WSB_OCAT  42467328u   // [BB][TT][1024] f32    18874368

// ---------------------------------------------------------------------------
// Generic 64x64-tile fp32 GEMM, A [M][K] row-major (or [K][M] col-major for
// MODE 1), W [N][K] row-major. 256 thr, 4x4/thread.
// MODE 0: conv_in + BN1 -> identity (ch-major) + r_t scale0 (tok-major)
// MODE 1: pointwise + BN2 -> r_t[scale] + ys_ch[scale-1]
// MODE 2: q/k/v projection (blockIdx.z selects W) -> f16 Q (log2e-scaled),
//         f16 K, f16 V^T
// MODE 3: output projection -> d_out
// ---------------------------------------------------------------------------
template<int MODE>
__global__ __launch_bounds__(256) void gemm64(
    const float* __restrict__ A,
    const float* __restrict__ W0, const float* __restrict__ W1, const float* __restrict__ W2,
    float* __restrict__ out, float* __restrict__ out2, float* __restrict__ out3,
    const float* __restrict__ bg, const float* __restrict__ bb,
    const float* __restrict__ bm, const float* __restrict__ bv,
    int Kdim, int scale_s)
{
    __shared__ __align__(16) float As[16][68];
    __shared__ __align__(16) float Ws[16][68];
    const int tid = threadIdx.x;
    const int m0 = blockIdx.x * 64;
    const int n0 = blockIdx.y * 64;
    const float* W = W0;
    if (MODE == 2) {
        if (blockIdx.z == 1) W = W1;
        else if (blockIdx.z == 2) W = W2;
    }
    const int tm = tid & 15, tn = tid >> 4;
    float acc[4][4] = {};
    for (int k0 = 0; k0 < Kdim; k0 += 16) {
        __syncthreads();
        if (MODE == 1) {
            const int kk = tid >> 4, mc = tid & 15;
            float4 a4 = *(const float4*)&A[(size_t)(k0 + kk) * (BB * TT) + m0 + mc * 4];
            *(float4*)&As[kk][mc * 4] = a4;
        } else {
            const int lr = tid >> 2, lc = tid & 3;
            float4 a4 = *(const float4*)&A[(size_t)(m0 + lr) * Kdim + k0 + lc * 4];
            As[lc * 4 + 0][lr] = a4.x; As[lc * 4 + 1][lr] = a4.y;
            As[lc * 4 + 2][lr] = a4.z; As[lc * 4 + 3][lr] = a4.w;
        }
        {
            const int lr = tid >> 2, lc = tid & 3;
            float4 w4 = *(const float4*)&W[(size_t)(n0 + lr) * Kdim + k0 + lc * 4];
            Ws[lc * 4 + 0][lr] = w4.x; Ws[lc * 4 + 1][lr] = w4.y;
            Ws[lc * 4 + 2][lr] = w4.z; Ws[lc * 4 + 3][lr] = w4.w;
        }
        __syncthreads();
        #pragma unroll
        for (int kk = 0; kk < 16; ++kk) {
            float4 af = *(const float4*)&As[kk][tm * 4];
            float4 wf = *(const float4*)&Ws[kk][tn * 4];
            float av[4] = {af.x, af.y, af.z, af.w};
            float wv[4] = {wf.x, wf.y, wf.z, wf.w};
            #pragma unroll
            for (int i = 0; i < 4; ++i)
                #pragma unroll
                for (int j = 0; j < 4; ++j)
                    acc[i][j] = fmaf(av[i], wv[j], acc[i][j]);
        }
    }

    if (MODE == 0) {
        #pragma unroll
        for (int j = 0; j < 4; ++j) {
            const int o = n0 + tn * 4 + j;
            const float inv = bg[o] * rsqrtf(bv[o] + EPSV);
            const float bet = bb[o] - bm[o] * inv;
            #pragma unroll
            for (int i = 0; i < 4; ++i) {
                const int m = m0 + tm * 4 + i;
                const int b = m / TT, t = m % TT;
                const float val = acc[i][j] * inv + bet;
                out[((size_t)(b * CIN + o)) * TT + t] = val;
                if (o < C4) out2[((size_t)(b * TT + t)) * C4 + o] = val;
            }
        }
    } else if (MODE == 1) {
        #pragma unroll
        for (int j = 0; j < 4; ++j) {
            const int o = n0 + tn * 4 + j;
            const float inv = bg[o] * rsqrtf(bv[o] + EPSV);
            const float bet = bb[o] - bm[o] * inv;
            #pragma unroll
            for (int i = 0; i < 4; ++i) {
                const int m = m0 + tm * 4 + i;
                const int b = m / TT, t = m % TT;
                const float val = acc[i][j] * inv + bet;
                out[(((size_t)scale_s * BB + b) * TT + t) * C4 + o] = val;
                out2[(((size_t)(scale_s - 1) * BB + b) * C4 + o) * TT + t] = val;
            }
        }
    } else if (MODE == 2) {
        const int z = blockIdx.z;
        const int h = n0 >> 6;
        #pragma unroll
        for (int i = 0; i < 4; ++i) {
            const int m = m0 + tm * 4 + i;
            const int s = m / (BB * TT);
            const int rem = m - s * (BB * TT);
            const int b = rem / TT, t = rem - (rem / TT) * TT;
            const int combo = (s * BB + b) * NHEADS + h;
            if (z == 0) {
                _Float16* dst = (_Float16*)out + ((size_t)combo * TT + t) * DHV + tn * 4;
                uint2 u;
                u.x = pk2(acc[i][0] * LOG2E, acc[i][1] * LOG2E);
                u.y = pk2(acc[i][2] * LOG2E, acc[i][3] * LOG2E);
                *(uint2*)dst = u;
            } else if (z == 1) {
                _Float16* dst = (_Float16*)out2 + ((size_t)combo * TT + t) * DHV + tn * 4;
                uint2 u;
                u.x = pk2(acc[i][0], acc[i][1]);
                u.y = pk2(acc[i][2], acc[i][3]);
                *(uint2*)dst = u;
            } else {
                _Float16* vtp = (_Float16*)out3;
                #pragma unroll
                for (int j = 0; j < 4; ++j)
                    vtp[((size_t)combo * DHV + tn * 4 + j) * TT + t] = (_Float16)acc[i][j];
            }
        }
    } else {
        #pragma unroll
        for (int i = 0; i < 4; ++i) {
            const int m = m0 + tm * 4 + i;
            float4 v4 = make_float4(acc[i][0], acc[i][1], acc[i][2], acc[i][3]);
            *(float4*)&out[(size_t)m * CIN + n0 + tn * 4] = v4;
        }
    }
}

// ---------------------------------------------------------------------------
// Depthwise 3x3 SAME, output col-major [C4][BB*TT].
// ---------------------------------------------------------------------------
__global__ __launch_bounds__(256) void dw3x3(
    const float* __restrict__ ident, const float* __restrict__ ysprev,
    const float* __restrict__ dww, float* __restrict__ dwt, int s)
{
    const int g = blockIdx.x * 256 + threadIdx.x;
    const int t = g % TT;
    const int c = (g / TT) & (C4 - 1);
    const int b = g / (TT * C4);
    const int h = t / WWW, w = t % WWW;
    const float* p1 = ident + ((size_t)(b * CIN + s * C4 + c)) * TT;
    const float* p2 = ysprev ? (ysprev + ((size_t)(b * C4 + c)) * TT) : nullptr;
    float acc = 0.f;
    #pragma unroll
    for (int kh = 0; kh < 3; ++kh) {
        const int hh2 = h + kh - 1;
        if (hh2 < 0 || hh2 >= HHH) continue;
        #pragma unroll
        for (int kw = 0; kw < 3; ++kw) {
            const int ww2 = w + kw - 1;
            if (ww2 < 0 || ww2 >= WWW) continue;
            const int t2 = hh2 * WWW + ww2;
            float v = p1[t2];
            if (p2) v += p2[t2];
            acc = fmaf(v, dww[c * 9 + kh * 3 + kw], acc);
        }
    }
    dwt[(size_t)c * (BB * TT) + b * TT + t] = acc;
}

// ---------------------------------------------------------------------------
// f16 MFMA flash attention (swapped operands, barrier-free).
// Block = 4 independent waves; each wave owns 32 q-rows of one combo.
// S^T = mfma(A=K_tile, B=Q^T): C-frag lane l holds S[q=l&15(+16qf)][kc=m*16+4g+r]
//   -> softmax rows are lane-local (16 in-lane values + shfl_xor 16/32).
// P written row-major [q][kc] to wave-private LDS (b64), read as B-frags (b128).
// O^T = mfma(A=V^T_tile, B=P): lane holds O[q=l&15(+16qf)][d=m*16+4g+r].
// Q (log2e-scaled), K, V^T frags read directly from row-major global (16B/lane).
// ---------------------------------------------------------------------------
__global__ __launch_bounds__(256) void attn_mfma(
    const _Float16* __restrict__ qh, const _Float16* __restrict__ kh,
    const _Float16* __restrict__ vt, float* __restrict__ ocat)
{
    __shared__ _Float16 Plds[4][32][88];   // pad 88 f16 = 176 B: conflict-free b128
    const int tid = threadIdx.x;
    const int wv = tid >> 6;
    const int lane = tid & 63;
    const int g = lane >> 4, ln = lane & 15;
    const int combo = blockIdx.y;
    const int q0 = (blockIdx.x * 4 + wv) * 32;
    const _Float16* Q = qh + (size_t)combo * TT * DHV;
    const _Float16* K = kh + (size_t)combo * TT * DHV;
    const _Float16* V = vt + (size_t)combo * DHV * TT;

    // Q B-frags, held for the whole kernel
    f16x8 bq[2][2];
    #pragma unroll
    for (int qf = 0; qf < 2; ++qf)
        #pragma unroll
        for (int k0 = 0; k0 < 2; ++k0)
            bq[qf][k0] = *(const f16x8*)(Q + ((size_t)(q0 + qf * 16 + ln)) * DHV + k0 * 32 + g * 8);

    f32x4 O[4][2] = {};
    float mrun[2] = {-1e30f, -1e30f}, lrun[2] = {0.f, 0.f};

    for (int kb = 0; kb < TT; kb += 64) {
        // ---- QK^T (swapped) ----
        f16x8 ak[4][2];
        #pragma unroll
        for (int m = 0; m < 4; ++m)
            #pragma unroll
            for (int k0 = 0; k0 < 2; ++k0)
                ak[m][k0] = *(const f16x8*)(K + ((size_t)(kb + m * 16 + ln)) * DHV + k0 * 32 + g * 8);
        f32x4 S[4][2] = {};
        #pragma unroll
        for (int m = 0; m < 4; ++m)
            #pragma unroll
            for (int qf = 0; qf < 2; ++qf) {
                S[m][qf] = __builtin_amdgcn_mfma_f32_16x16x32_f16(ak[m][0], bq[qf][0], S[m][qf], 0, 0, 0);
                S[m][qf] = __builtin_amdgcn_mfma_f32_16x16x32_f16(ak[m][1], bq[qf][1], S[m][qf], 0, 0, 0);
            }

        // ---- online softmax (rows lane-local; exp2 domain) ----
        #pragma unroll
        for (int qf = 0; qf < 2; ++qf) {
            float mx = S[0][qf][0];
            #pragma unroll
            for (int m = 0; m < 4; ++m)
                #pragma unroll
                for (int r = 0; r < 4; ++r)
                    mx = fmaxf(mx, S[m][qf][r]);
            mx = fmaxf(mx, __shfl_xor(mx, 16));
            mx = fmaxf(mx, __shfl_xor(mx, 32));
            const float mnew = fmaxf(mrun[qf], mx);
            const float corr = exp2f(mrun[qf] - mnew);
            float ps = 0.f;
            #pragma unroll
            for (int m = 0; m < 4; ++m)
                #pragma unroll
                for (int r = 0; r < 4; ++r) {
                    const float p = exp2f(S[m][qf][r] - mnew);
                    S[m][qf][r] = p; ps += p;
                }
            ps += __shfl_xor(ps, 16);
            ps += __shfl_xor(ps, 32);
            lrun[qf] = lrun[qf] * corr + ps;
            mrun[qf] = mnew;
            #pragma unroll
            for (int m = 0; m < 4; ++m) O[m][qf] *= corr;
            #pragma unroll
            for (int m = 0; m < 4; ++m) {
                uint2 u;
                u.x = pk2(S[m][qf][0], S[m][qf][1]);
                u.y = pk2(S[m][qf][2], S[m][qf][3]);
                *(uint2*)&Plds[wv][qf * 16 + ln][m * 16 + g * 4] = u;
            }
        }

        // ---- PV (swapped): O^T += V^T_blk . P ----
        f16x8 bp[2][2];
        #pragma unroll
        for (int qf = 0; qf < 2; ++qf)
            #pragma unroll
            for (int kc0 = 0; kc0 < 2; ++kc0)
                bp[qf][kc0] = *(const f16x8*)&Plds[wv][qf * 16 + ln][kc0 * 32 + g * 8];
        #pragma unroll
        for (int m = 0; m < 4; ++m) {
            #pragma unroll
            for (int kc0 = 0; kc0 < 2; ++kc0) {
                f16x8 av = *(const f16x8*)(V + ((size_t)(m * 16 + ln)) * TT + kb + kc0 * 32 + g * 8);
                #pragma unroll
                for (int qf = 0; qf < 2; ++qf)
                    O[m][qf] = __builtin_amdgcn_mfma_f32_16x16x32_f16(av, bp[qf][kc0], O[m][qf], 0, 0, 0);
            }
        }
    }

    // ---- epilogue ----
    const int s_ = combo >> 3, b_ = (combo >> 2) & 1, h_ = combo & 3;
    #pragma unroll
    for (int qf = 0; qf < 2; ++qf) {
        const float inv = 1.f / lrun[qf];
        const int tok = q0 + qf * 16 + ln;
        #pragma unroll
        for (int m = 0; m < 4; ++m) {
            f32x4 ov = O[m][qf] * inv;
            *(f32x4*)&ocat[((size_t)(b_ * TT + tok)) * 1024 + s_ * 256 + h_ * 64 + m * 16 + g * 4] = ov;
        }
    }
}

// ---------------------------------------------------------------------------
extern "C" void kernel_launch(void* const* d_in, const int* in_sizes, int n_in,
                              void* d_out, int out_size, void* d_ws, size_t ws_size,
                              hipStream_t stream)
{
    const float* x    = (const float*)d_in[0];
    const float* wci  = (const float*)d_in[1];
    const float* b1g  = (const float*)d_in[2];
    const float* b1b  = (const float*)d_in[3];
    const float* b1m  = (const float*)d_in[4];
    const float* b1v  = (const float*)d_in[5];
    const float* dww  = (const float*)d_in[6];
    const float* pww  = (const float*)d_in[7];
    const float* b2g  = (const float*)d_in[8];
    const float* b2b  = (const float*)d_in[9];
    const float* b2m  = (const float*)d_in[10];
    const float* b2v  = (const float*)d_in[11];
    const float* Wq   = (const float*)d_in[12];
    const float* Wk   = (const float*)d_in[13];
    const float* Wv   = (const float*)d_in[14];
    const float* Wout = (const float*)d_in[15];

    char* wsb = (char*)d_ws;
    float*     ident = (float*)(wsb + WSB_IDENT);
    float*     rt    = (float*)(wsb + WSB_RT);
    float*     dwt   = (float*)(wsb + WSB_DWT);
    float*     ysch  = (float*)(wsb + WSB_YS);
    _Float16*  qh    = (_Float16*)(wsb + WSB_QH);
    _Float16*  khp   = (_Float16*)(wsb + WSB_KH);
    _Float16*  vtp   = (_Float16*)(wsb + WSB_VT);
    float*     ocat  = (float*)(wsb + WSB_OCAT);
    float*     outp  = (float*)d_out;

    // 1) conv_in (1x1) + BN1
    gemm64<0><<<dim3(BB * TT / 64, CIN / 64), 256, 0, stream>>>(
        x, wci, nullptr, nullptr, ident, rt, nullptr, b1g, b1b, b1m, b1v, CIN, 0);

    // 2) Res2Net chain: dw3x3 -> pw 1x1 + BN2, scales 1..3 (sequential)
    for (int s = 1; s <= 3; ++s) {
        const float* yp = (s == 1) ? nullptr : (ysch + (size_t)(s - 2) * BB * C4 * TT);
        dw3x3<<<dim3(BB * C4 * TT / 256), 256, 0, stream>>>(ident, yp, dww, dwt, s);
        gemm64<1><<<dim3(BB * TT / 64, 1), 256, 0, stream>>>(
            dwt, pww, nullptr, nullptr, rt, ysch, nullptr, b2g, b2b, b2m, b2v, C4, s);
    }

    // 3) q/k/v projections -> f16 Q(log2e-scaled), K, V^T
    gemm64<2><<<dim3(4 * BB * TT / 64, CIN / 64, 3), 256, 0, stream>>>(
        rt, Wq, Wk, Wv, (float*)qh, (float*)khp, (float*)vtp,
        nullptr, nullptr, nullptr, nullptr, C4, 0);

    // 4) f16 MFMA flash attention -> concatenated o [B][T][1024] fp32
    attn_mfma<<<dim3(TT / 32 / 4, 32), 256, 0, stream>>>(qh, khp, vtp, ocat);

    // 5) output projection -> d_out
    gemm64<3><<<dim3(BB * TT / 64, CIN / 64), 256, 0, stream>>>(
        ocat, Wout, nullptr, nullptr, outp, nullptr, nullptr,
        nullptr, nullptr, nullptr, nullptr, 4 * CIN, 0);
}

// Round 8
// 347.399 us; speedup vs baseline: 2.2967x; 1.1929x over previous
//
#include <hip/hip_runtime.h>
#include <math.h>

#define BB 2
#define TT 2304
#define CIN 256
#define C4 64
#define NHEADS 4
#define DHV 64
#define HHH 48
#define WWW 48
#define EPSV 1e-5f
#define LOG2E 1.4426950408889634f

using f16x8 = __attribute__((ext_vector_type(8))) _Float16;
using f32x4 = __attribute__((ext_vector_type(4))) float;

// pack two f32 -> one u32 of two f16 (RTZ), type-safe via bit_cast
__device__ __forceinline__ unsigned pk2(float a, float b) {
    return __builtin_bit_cast(unsigned, __builtin_amdgcn_cvt_pkrtz(a, b));
}

// workspace layout (byte offsets)
#define WSB_IDENT 0u          // [BB][CIN][TT] f32      4718592
#define WSB_RT    4718592u    // [4][BB][TT][C4] f32    4718592
#define WSB_DWT   9437184u    // [C4][BB*TT] f32        1179648
#define WSB_YS    10616832u   // [3][BB][C4][TT] f32    3538944
#define WSB_QH    14155776u   // [32][TT][64] f16       9437184  (pre-scaled by log2e)
#define WSB_KH    23592960u   // [32][TT][64] f16       9437184
#define WSB_VT    33030144u   // [32][64][TT] f16       9437184  (V transposed)
#define WSB_OCAT  42467328u   // [BB][TT][1024] f32    18874368

// ---------------------------------------------------------------------------
// Generic 64x64-tile fp32 GEMM, A [M][K] row-major (or [K][M] col-major for
// MODE 1), W [N][K] row-major. 256 thr, 4x4/thread.
// MODE 0: conv_in + BN1 -> identity (ch-major) + r_t scale0 (tok-major)
// MODE 1: pointwise + BN2 -> r_t[scale] + ys_ch[scale-1]
// MODE 2: q/k/v projection (blockIdx.z selects W) -> f16 Q (log2e-scaled),
//         f16 K, f16 V^T
// MODE 3: output projection -> d_out
// ---------------------------------------------------------------------------
template<int MODE>
__global__ __launch_bounds__(256) void gemm64(
    const float* __restrict__ A,
    const float* __restrict__ W0, const float* __restrict__ W1, const float* __restrict__ W2,
    float* __restrict__ out, float* __restrict__ out2, float* __restrict__ out3,
    const float* __restrict__ bg, const float* __restrict__ bb,
    const float* __restrict__ bm, const float* __restrict__ bv,
    int Kdim, int scale_s)
{
    __shared__ __align__(16) float As[16][68];
    __shared__ __align__(16) float Ws[16][68];
    const int tid = threadIdx.x;
    const int m0 = blockIdx.x * 64;
    const int n0 = blockIdx.y * 64;
    const float* W = W0;
    if (MODE == 2) {
        if (blockIdx.z == 1) W = W1;
        else if (blockIdx.z == 2) W = W2;
    }
    const int tm = tid & 15, tn = tid >> 4;
    float acc[4][4] = {};
    for (int k0 = 0; k0 < Kdim; k0 += 16) {
        __syncthreads();
        if (MODE == 1) {
            const int kk = tid >> 4, mc = tid & 15;
            float4 a4 = *(const float4*)&A[(size_t)(k0 + kk) * (BB * TT) + m0 + mc * 4];
            *(float4*)&As[kk][mc * 4] = a4;
        } else {
            const int lr = tid >> 2, lc = tid & 3;
            float4 a4 = *(const float4*)&A[(size_t)(m0 + lr) * Kdim + k0 + lc * 4];
            As[lc * 4 + 0][lr] = a4.x; As[lc * 4 + 1][lr] = a4.y;
            As[lc * 4 + 2][lr] = a4.z; As[lc * 4 + 3][lr] = a4.w;
        }
        {
            const int lr = tid >> 2, lc = tid & 3;
            float4 w4 = *(const float4*)&W[(size_t)(n0 + lr) * Kdim + k0 + lc * 4];
            Ws[lc * 4 + 0][lr] = w4.x; Ws[lc * 4 + 1][lr] = w4.y;
            Ws[lc * 4 + 2][lr] = w4.z; Ws[lc * 4 + 3][lr] = w4.w;
        }
        __syncthreads();
        #pragma unroll
        for (int kk = 0; kk < 16; ++kk) {
            float4 af = *(const float4*)&As[kk][tm * 4];
            float4 wf = *(const float4*)&Ws[kk][tn * 4];
            float av[4] = {af.x, af.y, af.z, af.w};
            float wv[4] = {wf.x, wf.y, wf.z, wf.w};
            #pragma unroll
            for (int i = 0; i < 4; ++i)
                #pragma unroll
                for (int j = 0; j < 4; ++j)
                    acc[i][j] = fmaf(av[i], wv[j], acc[i][j]);
        }
    }

    if (MODE == 0) {
        #pragma unroll
        for (int j = 0; j < 4; ++j) {
            const int o = n0 + tn * 4 + j;
            const float inv = bg[o] * rsqrtf(bv[o] + EPSV);
            const float bet = bb[o] - bm[o] * inv;
            #pragma unroll
            for (int i = 0; i < 4; ++i) {
                const int m = m0 + tm * 4 + i;
                const int b = m / TT, t = m % TT;
                const float val = acc[i][j] * inv + bet;
                out[((size_t)(b * CIN + o)) * TT + t] = val;
                if (o < C4) out2[((size_t)(b * TT + t)) * C4 + o] = val;
            }
        }
    } else if (MODE == 1) {
        #pragma unroll
        for (int j = 0; j < 4; ++j) {
            const int o = n0 + tn * 4 + j;
            const float inv = bg[o] * rsqrtf(bv[o] + EPSV);
            const float bet = bb[o] - bm[o] * inv;
            #pragma unroll
            for (int i = 0; i < 4; ++i) {
                const int m = m0 + tm * 4 + i;
                const int b = m / TT, t = m % TT;
                const float val = acc[i][j] * inv + bet;
                out[(((size_t)scale_s * BB + b) * TT + t) * C4 + o] = val;
                out2[(((size_t)(scale_s - 1) * BB + b) * C4 + o) * TT + t] = val;
            }
        }
    } else if (MODE == 2) {
        const int z = blockIdx.z;
        const int h = n0 >> 6;
        #pragma unroll
        for (int i = 0; i < 4; ++i) {
            const int m = m0 + tm * 4 + i;
            const int s = m / (BB * TT);
            const int rem = m - s * (BB * TT);
            const int b = rem / TT, t = rem - (rem / TT) * TT;
            const int combo = (s * BB + b) * NHEADS + h;
            if (z == 0) {
                _Float16* dst = (_Float16*)out + ((size_t)combo * TT + t) * DHV + tn * 4;
                uint2 u;
                u.x = pk2(acc[i][0] * LOG2E, acc[i][1] * LOG2E);
                u.y = pk2(acc[i][2] * LOG2E, acc[i][3] * LOG2E);
                *(uint2*)dst = u;
            } else if (z == 1) {
                _Float16* dst = (_Float16*)out2 + ((size_t)combo * TT + t) * DHV + tn * 4;
                uint2 u;
                u.x = pk2(acc[i][0], acc[i][1]);
                u.y = pk2(acc[i][2], acc[i][3]);
                *(uint2*)dst = u;
            } else {
                _Float16* vtp = (_Float16*)out3;
                #pragma unroll
                for (int j = 0; j < 4; ++j)
                    vtp[((size_t)combo * DHV + tn * 4 + j) * TT + t] = (_Float16)acc[i][j];
            }
        }
    } else {
        #pragma unroll
        for (int i = 0; i < 4; ++i) {
            const int m = m0 + tm * 4 + i;
            float4 v4 = make_float4(acc[i][0], acc[i][1], acc[i][2], acc[i][3]);
            *(float4*)&out[(size_t)m * CIN + n0 + tn * 4] = v4;
        }
    }
}

// ---------------------------------------------------------------------------
// Depthwise 3x3 SAME, output col-major [C4][BB*TT].
// ---------------------------------------------------------------------------
__global__ __launch_bounds__(256) void dw3x3(
    const float* __restrict__ ident, const float* __restrict__ ysprev,
    const float* __restrict__ dww, float* __restrict__ dwt, int s)
{
    const int g = blockIdx.x * 256 + threadIdx.x;
    const int t = g % TT;
    const int c = (g / TT) & (C4 - 1);
    const int b = g / (TT * C4);
    const int h = t / WWW, w = t % WWW;
    const float* p1 = ident + ((size_t)(b * CIN + s * C4 + c)) * TT;
    const float* p2 = ysprev ? (ysprev + ((size_t)(b * C4 + c)) * TT) : nullptr;
    float acc = 0.f;
    #pragma unroll
    for (int kh = 0; kh < 3; ++kh) {
        const int hh2 = h + kh - 1;
        if (hh2 < 0 || hh2 >= HHH) continue;
        #pragma unroll
        for (int kw = 0; kw < 3; ++kw) {
            const int ww2 = w + kw - 1;
            if (ww2 < 0 || ww2 >= WWW) continue;
            const int t2 = hh2 * WWW + ww2;
            float v = p1[t2];
            if (p2) v += p2[t2];
            acc = fmaf(v, dww[c * 9 + kh * 3 + kw], acc);
        }
    }
    dwt[(size_t)c * (BB * TT) + b * TT + t] = acc;
}

// ---------------------------------------------------------------------------
// f16 MFMA flash attention (swapped operands), register-pipelined.
// Block = 4 waves, same combo (blockIdx.y); each wave owns 32 q-rows.
// Pipeline: at iteration top, issue V(kb) and K(kb+64) frag loads; QK^T uses
// K frags loaded LAST iteration -> both global-load phases (~200-400cy L2
// latency) overlap QK^T+softmax+PV compute (~600+cy). Raw s_barrier per tile
// keeps the 4 waves converged on the same K/V tile for L1 reuse (no cross-
// wave LDS data -> no waitcnt semantics required).
// S^T = mfma(A=K_tile, B=Q^T): softmax rows lane-local (16 vals + 2 shfl).
// P round-trips wave-private LDS (b64 write, b128 read) to become B-frags.
// O^T = mfma(A=V^T_tile, B=P).
// ---------------------------------------------------------------------------
__global__ __launch_bounds__(256, 2) void attn_mfma(
    const _Float16* __restrict__ qh, const _Float16* __restrict__ kh,
    const _Float16* __restrict__ vt, float* __restrict__ ocat)
{
    __shared__ _Float16 Plds[4][32][88];   // pad 88 f16 = 176 B: conflict-free-ish b128
    const int tid = threadIdx.x;
    const int wv = tid >> 6;
    const int lane = tid & 63;
    const int g = lane >> 4, ln = lane & 15;
    const int combo = blockIdx.y;
    const int q0 = (blockIdx.x * 4 + wv) * 32;
    const _Float16* Q = qh + (size_t)combo * TT * DHV;
    const _Float16* K = kh + (size_t)combo * TT * DHV;
    const _Float16* V = vt + (size_t)combo * DHV * TT;

    // Q B-frags, held for the whole kernel
    f16x8 bq[2][2];
    #pragma unroll
    for (int qf = 0; qf < 2; ++qf)
        #pragma unroll
        for (int k0 = 0; k0 < 2; ++k0)
            bq[qf][k0] = *(const f16x8*)(Q + ((size_t)(q0 + qf * 16 + ln)) * DHV + k0 * 32 + g * 8);

    f32x4 O[4][2] = {};
    float mrun[2] = {-1e30f, -1e30f}, lrun[2] = {0.f, 0.f};

    // preload K frags for tile 0
    f16x8 akc[4][2];
    #pragma unroll
    for (int m = 0; m < 4; ++m)
        #pragma unroll
        for (int k0 = 0; k0 < 2; ++k0)
            akc[m][k0] = *(const f16x8*)(K + ((size_t)(m * 16 + ln)) * DHV + k0 * 32 + g * 8);

    #pragma unroll 2
    for (int kb = 0; kb < TT; kb += 64) {
        const int kbn = (kb + 64 < TT) ? kb + 64 : 0;   // clamped (last-iter value unused)

        // ---- issue V(kb) + K(kb+64) loads NOW; consumed 600+/1200+ cyc later ----
        f16x8 av[4][2], akn[4][2];
        #pragma unroll
        for (int m = 0; m < 4; ++m)
            #pragma unroll
            for (int kc0 = 0; kc0 < 2; ++kc0)
                av[m][kc0] = *(const f16x8*)(V + ((size_t)(m * 16 + ln)) * TT + kb + kc0 * 32 + g * 8);
        #pragma unroll
        for (int m = 0; m < 4; ++m)
            #pragma unroll
            for (int k0 = 0; k0 < 2; ++k0)
                akn[m][k0] = *(const f16x8*)(K + ((size_t)(kbn + m * 16 + ln)) * DHV + k0 * 32 + g * 8);

        // ---- QK^T (swapped) on the K frags loaded last iteration ----
        f32x4 S[4][2] = {};
        #pragma unroll
        for (int m = 0; m < 4; ++m)
            #pragma unroll
            for (int qf = 0; qf < 2; ++qf) {
                S[m][qf] = __builtin_amdgcn_mfma_f32_16x16x32_f16(akc[m][0], bq[qf][0], S[m][qf], 0, 0, 0);
                S[m][qf] = __builtin_amdgcn_mfma_f32_16x16x32_f16(akc[m][1], bq[qf][1], S[m][qf], 0, 0, 0);
            }

        // ---- online softmax (rows lane-local; exp2 domain) ----
        #pragma unroll
        for (int qf = 0; qf < 2; ++qf) {
            float mx = S[0][qf][0];
            #pragma unroll
            for (int m = 0; m < 4; ++m)
                #pragma unroll
                for (int r = 0; r < 4; ++r)
                    mx = fmaxf(mx, S[m][qf][r]);
            mx = fmaxf(mx, __shfl_xor(mx, 16));
            mx = fmaxf(mx, __shfl_xor(mx, 32));
            const float mnew = fmaxf(mrun[qf], mx);
            const float corr = exp2f(mrun[qf] - mnew);
            float ps = 0.f;
            #pragma unroll
            for (int m = 0; m < 4; ++m)
                #pragma unroll
                for (int r = 0; r < 4; ++r) {
                    const float p = exp2f(S[m][qf][r] - mnew);
                    S[m][qf][r] = p; ps += p;
                }
            ps += __shfl_xor(ps, 16);
            ps += __shfl_xor(ps, 32);
            lrun[qf] = lrun[qf] * corr + ps;
            mrun[qf] = mnew;
            #pragma unroll
            for (int m = 0; m < 4; ++m) O[m][qf] *= corr;
            #pragma unroll
            for (int m = 0; m < 4; ++m) {
                uint2 u;
                u.x = pk2(S[m][qf][0], S[m][qf][1]);
                u.y = pk2(S[m][qf][2], S[m][qf][3]);
                *(uint2*)&Plds[wv][qf * 16 + ln][m * 16 + g * 4] = u;
            }
        }

        // ---- PV (swapped): O^T += V^T_blk . P, V frags already in regs ----
        f16x8 bp[2][2];
        #pragma unroll
        for (int qf = 0; qf < 2; ++qf)
            #pragma unroll
            for (int kc0 = 0; kc0 < 2; ++kc0)
                bp[qf][kc0] = *(const f16x8*)&Plds[wv][qf * 16 + ln][kc0 * 32 + g * 8];
        #pragma unroll
        for (int m = 0; m < 4; ++m)
            #pragma unroll
            for (int kc0 = 0; kc0 < 2; ++kc0)
                #pragma unroll
                for (int qf = 0; qf < 2; ++qf)
                    O[m][qf] = __builtin_amdgcn_mfma_f32_16x16x32_f16(av[m][kc0], bp[qf][kc0], O[m][qf], 0, 0, 0);

        // rotate K prefetch regs
        #pragma unroll
        for (int m = 0; m < 4; ++m)
            #pragma unroll
            for (int k0 = 0; k0 < 2; ++k0)
                akc[m][k0] = akn[m][k0];

        // keep the block's 4 waves time-converged for L1 reuse (no data dep)
        __builtin_amdgcn_s_barrier();
    }

    // ---- epilogue ----
    const int s_ = combo >> 3, b_ = (combo >> 2) & 1, h_ = combo & 3;
    #pragma unroll
    for (int qf = 0; qf < 2; ++qf) {
        const float inv = 1.f / lrun[qf];
        const int tok = q0 + qf * 16 + ln;
        #pragma unroll
        for (int m = 0; m < 4; ++m) {
            f32x4 ov = O[m][qf] * inv;
            *(f32x4*)&ocat[((size_t)(b_ * TT + tok)) * 1024 + s_ * 256 + h_ * 64 + m * 16 + g * 4] = ov;
        }
    }
}

// ---------------------------------------------------------------------------
extern "C" void kernel_launch(void* const* d_in, const int* in_sizes, int n_in,
                              void* d_out, int out_size, void* d_ws, size_t ws_size,
                              hipStream_t stream)
{
    const float* x    = (const float*)d_in[0];
    const float* wci  = (const float*)d_in[1];
    const float* b1g  = (const float*)d_in[2];
    const float* b1b  = (const float*)d_in[3];
    const float* b1m  = (const float*)d_in[4];
    const float* b1v  = (const float*)d_in[5];
    const float* dww  = (const float*)d_in[6];
    const float* pww  = (const float*)d_in[7];
    const float* b2g  = (const float*)d_in[8];
    const float* b2b  = (const float*)d_in[9];
    const float* b2m  = (const float*)d_in[10];
    const float* b2v  = (const float*)d_in[11];
    const float* Wq   = (const float*)d_in[12];
    const float* Wk   = (const float*)d_in[13];
    const float* Wv   = (const float*)d_in[14];
    const float* Wout = (const float*)d_in[15];

    char* wsb = (char*)d_ws;
    float*     ident = (float*)(wsb + WSB_IDENT);
    float*     rt    = (float*)(wsb + WSB_RT);
    float*     dwt   = (float*)(wsb + WSB_DWT);
    float*     ysch  = (float*)(wsb + WSB_YS);
    _Float16*  qh    = (_Float16*)(wsb + WSB_QH);
    _Float16*  khp   = (_Float16*)(wsb + WSB_KH);
    _Float16*  vtp   = (_Float16*)(wsb + WSB_VT);
    float*     ocat  = (float*)(wsb + WSB_OCAT);
    float*     outp  = (float*)d_out;

    // 1) conv_in (1x1) + BN1
    gemm64<0><<<dim3(BB * TT / 64, CIN / 64), 256, 0, stream>>>(
        x, wci, nullptr, nullptr, ident, rt, nullptr, b1g, b1b, b1m, b1v, CIN, 0);

    // 2) Res2Net chain: dw3x3 -> pw 1x1 + BN2, scales 1..3 (sequential)
    for (int s = 1; s <= 3; ++s) {
        const float* yp = (s == 1) ? nullptr : (ysch + (size_t)(s - 2) * BB * C4 * TT);
        dw3x3<<<dim3(BB * C4 * TT / 256), 256, 0, stream>>>(ident, yp, dww, dwt, s);
        gemm64<1><<<dim3(BB * TT / 64, 1), 256, 0, stream>>>(
            dwt, pww, nullptr, nullptr, rt, ysch, nullptr, b2g, b2b, b2m, b2v, C4, s);
    }

    // 3) q/k/v projections -> f16 Q(log2e-scaled), K, V^T
    gemm64<2><<<dim3(4 * BB * TT / 64, CIN / 64, 3), 256, 0, stream>>>(
        rt, Wq, Wk, Wv, (float*)qh, (float*)khp, (float*)vtp,
        nullptr, nullptr, nullptr, nullptr, C4, 0);

    // 4) f16 MFMA flash attention -> concatenated o [B][T][1024] fp32
    attn_mfma<<<dim3(TT / 32 / 4, 32), 256, 0, stream>>>(qh, khp, vtp, ocat);

    // 5) output projection -> d_out
    gemm64<3><<<dim3(BB * TT / 64, CIN / 64), 256, 0, stream>>>(
        ocat, Wout, nullptr, nullptr, outp, nullptr, nullptr,
        nullptr, nullptr, nullptr, nullptr, 4 * CIN, 0);
}

// Round 9
// 316.011 us; speedup vs baseline: 2.5248x; 1.0993x over previous
//
#include <hip/hip_runtime.h>
#include <math.h>

#define BB 2
#define TT 2304
#define CIN 256
#define C4 64
#define NHEADS 4
#define DHV 64
#define HHH 48
#define WWW 48
#define EPSV 1e-5f
#define LOG2E 1.4426950408889634f
#define KSPLIT 4
#define KCHUNK (TT / KSPLIT)   // 576 keys = 9 tiles of 64 per wave

using f16x8 = __attribute__((ext_vector_type(8))) _Float16;
using f32x4 = __attribute__((ext_vector_type(4))) float;

// pack two f32 -> one u32 of two f16 (RTZ), type-safe via bit_cast
__device__ __forceinline__ unsigned pk2(float a, float b) {
    return __builtin_bit_cast(unsigned, __builtin_amdgcn_cvt_pkrtz(a, b));
}

// workspace layout (byte offsets)
#define WSB_IDENT 0u          // [BB][CIN][TT] f32      4718592
#define WSB_RT    4718592u    // [4][BB][TT][C4] f32    4718592
#define WSB_DWT   9437184u    // [C4][BB*TT] f32        1179648
#define WSB_YS    10616832u   // [3][BB][C4][TT] f32    3538944
#define WSB_QH    14155776u   // [32][TT][64] f16       9437184  (pre-scaled by log2e)
#define WSB_KH    23592960u   // [32][TT][64] f16       9437184
#define WSB_VT    33030144u   // [32][64][TT] f16       9437184  (V transposed)
#define WSB_OCAT  42467328u   // [BB][TT][1024] f32    18874368

// ---------------------------------------------------------------------------
// Generic 64x64-tile fp32 GEMM, A [M][K] row-major (or [K][M] col-major for
// MODE 1), W [N][K] row-major. 256 thr, 4x4/thread.
// MODE 0: conv_in + BN1 -> identity (ch-major) + r_t scale0 (tok-major)
// MODE 1: pointwise + BN2 -> r_t[scale] + ys_ch[scale-1]
// MODE 2: q/k/v projection (blockIdx.z selects W) -> f16 Q (log2e-scaled),
//         f16 K, f16 V^T
// MODE 3: output projection -> d_out
// ---------------------------------------------------------------------------
template<int MODE>
__global__ __launch_bounds__(256) void gemm64(
    const float* __restrict__ A,
    const float* __restrict__ W0, const float* __restrict__ W1, const float* __restrict__ W2,
    float* __restrict__ out, float* __restrict__ out2, float* __restrict__ out3,
    const float* __restrict__ bg, const float* __restrict__ bb,
    const float* __restrict__ bm, const float* __restrict__ bv,
    int Kdim, int scale_s)
{
    __shared__ __align__(16) float As[16][68];
    __shared__ __align__(16) float Ws[16][68];
    const int tid = threadIdx.x;
    const int m0 = blockIdx.x * 64;
    const int n0 = blockIdx.y * 64;
    const float* W = W0;
    if (MODE == 2) {
        if (blockIdx.z == 1) W = W1;
        else if (blockIdx.z == 2) W = W2;
    }
    const int tm = tid & 15, tn = tid >> 4;
    float acc[4][4] = {};
    for (int k0 = 0; k0 < Kdim; k0 += 16) {
        __syncthreads();
        if (MODE == 1) {
            const int kk = tid >> 4, mc = tid & 15;
            float4 a4 = *(const float4*)&A[(size_t)(k0 + kk) * (BB * TT) + m0 + mc * 4];
            *(float4*)&As[kk][mc * 4] = a4;
        } else {
            const int lr = tid >> 2, lc = tid & 3;
            float4 a4 = *(const float4*)&A[(size_t)(m0 + lr) * Kdim + k0 + lc * 4];
            As[lc * 4 + 0][lr] = a4.x; As[lc * 4 + 1][lr] = a4.y;
            As[lc * 4 + 2][lr] = a4.z; As[lc * 4 + 3][lr] = a4.w;
        }
        {
            const int lr = tid >> 2, lc = tid & 3;
            float4 w4 = *(const float4*)&W[(size_t)(n0 + lr) * Kdim + k0 + lc * 4];
            Ws[lc * 4 + 0][lr] = w4.x; Ws[lc * 4 + 1][lr] = w4.y;
            Ws[lc * 4 + 2][lr] = w4.z; Ws[lc * 4 + 3][lr] = w4.w;
        }
        __syncthreads();
        #pragma unroll
        for (int kk = 0; kk < 16; ++kk) {
            float4 af = *(const float4*)&As[kk][tm * 4];
            float4 wf = *(const float4*)&Ws[kk][tn * 4];
            float av[4] = {af.x, af.y, af.z, af.w};
            float wv[4] = {wf.x, wf.y, wf.z, wf.w};
            #pragma unroll
            for (int i = 0; i < 4; ++i)
                #pragma unroll
                for (int j = 0; j < 4; ++j)
                    acc[i][j] = fmaf(av[i], wv[j], acc[i][j]);
        }
    }

    if (MODE == 0) {
        #pragma unroll
        for (int j = 0; j < 4; ++j) {
            const int o = n0 + tn * 4 + j;
            const float inv = bg[o] * rsqrtf(bv[o] + EPSV);
            const float bet = bb[o] - bm[o] * inv;
            #pragma unroll
            for (int i = 0; i < 4; ++i) {
                const int m = m0 + tm * 4 + i;
                const int b = m / TT, t = m % TT;
                const float val = acc[i][j] * inv + bet;
                out[((size_t)(b * CIN + o)) * TT + t] = val;
                if (o < C4) out2[((size_t)(b * TT + t)) * C4 + o] = val;
            }
        }
    } else if (MODE == 1) {
        #pragma unroll
        for (int j = 0; j < 4; ++j) {
            const int o = n0 + tn * 4 + j;
            const float inv = bg[o] * rsqrtf(bv[o] + EPSV);
            const float bet = bb[o] - bm[o] * inv;
            #pragma unroll
            for (int i = 0; i < 4; ++i) {
                const int m = m0 + tm * 4 + i;
                const int b = m / TT, t = m % TT;
                const float val = acc[i][j] * inv + bet;
                out[(((size_t)scale_s * BB + b) * TT + t) * C4 + o] = val;
                out2[(((size_t)(scale_s - 1) * BB + b) * C4 + o) * TT + t] = val;
            }
        }
    } else if (MODE == 2) {
        const int z = blockIdx.z;
        const int h = n0 >> 6;
        #pragma unroll
        for (int i = 0; i < 4; ++i) {
            const int m = m0 + tm * 4 + i;
            const int s = m / (BB * TT);
            const int rem = m - s * (BB * TT);
            const int b = rem / TT, t = rem - (rem / TT) * TT;
            const int combo = (s * BB + b) * NHEADS + h;
            if (z == 0) {
                _Float16* dst = (_Float16*)out + ((size_t)combo * TT + t) * DHV + tn * 4;
                uint2 u;
                u.x = pk2(acc[i][0] * LOG2E, acc[i][1] * LOG2E);
                u.y = pk2(acc[i][2] * LOG2E, acc[i][3] * LOG2E);
                *(uint2*)dst = u;
            } else if (z == 1) {
                _Float16* dst = (_Float16*)out2 + ((size_t)combo * TT + t) * DHV + tn * 4;
                uint2 u;
                u.x = pk2(acc[i][0], acc[i][1]);
                u.y = pk2(acc[i][2], acc[i][3]);
                *(uint2*)dst = u;
            } else {
                _Float16* vtp = (_Float16*)out3;
                #pragma unroll
                for (int j = 0; j < 4; ++j)
                    vtp[((size_t)combo * DHV + tn * 4 + j) * TT + t] = (_Float16)acc[i][j];
            }
        }
    } else {
        #pragma unroll
        for (int i = 0; i < 4; ++i) {
            const int m = m0 + tm * 4 + i;
            float4 v4 = make_float4(acc[i][0], acc[i][1], acc[i][2], acc[i][3]);
            *(float4*)&out[(size_t)m * CIN + n0 + tn * 4] = v4;
        }
    }
}

// ---------------------------------------------------------------------------
// Depthwise 3x3 SAME, output col-major [C4][BB*TT].
// ---------------------------------------------------------------------------
__global__ __launch_bounds__(256) void dw3x3(
    const float* __restrict__ ident, const float* __restrict__ ysprev,
    const float* __restrict__ dww, float* __restrict__ dwt, int s)
{
    const int g = blockIdx.x * 256 + threadIdx.x;
    const int t = g % TT;
    const int c = (g / TT) & (C4 - 1);
    const int b = g / (TT * C4);
    const int h = t / WWW, w = t % WWW;
    const float* p1 = ident + ((size_t)(b * CIN + s * C4 + c)) * TT;
    const float* p2 = ysprev ? (ysprev + ((size_t)(b * C4 + c)) * TT) : nullptr;
    float acc = 0.f;
    #pragma unroll
    for (int kh = 0; kh < 3; ++kh) {
        const int hh2 = h + kh - 1;
        if (hh2 < 0 || hh2 >= HHH) continue;
        #pragma unroll
        for (int kw = 0; kw < 3; ++kw) {
            const int ww2 = w + kw - 1;
            if (ww2 < 0 || ww2 >= WWW) continue;
            const int t2 = hh2 * WWW + ww2;
            float v = p1[t2];
            if (p2) v += p2[t2];
            acc = fmaf(v, dww[c * 9 + kh * 3 + kw], acc);
        }
    }
    dwt[(size_t)c * (BB * TT) + b * TT + t] = acc;
}

// ---------------------------------------------------------------------------
// f16 MFMA flash attention, in-block k-split for occupancy.
// Block = 4 waves sharing ONE 32-row q-tile of one combo; wave w processes
// keys [w*576, (w+1)*576) (9 tiles of 64) with private online softmax, then
// the 4 partials (m,l,O) merge through LDS. Grid 72x32 = 2304 blocks = 9216
// waves (4x round 8) -> up to 4 waves/SIMD to hide the per-tile serial chain.
// S^T = mfma(A=K_tile, B=Q^T): softmax rows lane-local (tree + 2 shfl_xor).
// P round-trips wave-private LDS to become PV B-frags; O^T = mfma(A=V^T,B=P).
// Obuf for the merge aliases the (dead-by-then) Plds region.
// ---------------------------------------------------------------------------
__global__ __launch_bounds__(256, 4) void attn_mfma(
    const _Float16* __restrict__ qh, const _Float16* __restrict__ kh,
    const _Float16* __restrict__ vt, float* __restrict__ ocat)
{
    __shared__ __align__(16) char smemraw[22528];  // Plds [4][32][88]f16 / Obuf [2][32][68]f32
    __shared__ float mlbuf[KSPLIT][2][16][2];
    _Float16 (*Plds)[32][88] = (_Float16(*)[32][88])smemraw;
    float (*Obuf)[32][68] = (float(*)[32][68])smemraw;

    const int tid = threadIdx.x;
    const int wv = tid >> 6;
    const int lane = tid & 63;
    const int g = lane >> 4, ln = lane & 15;
    const int combo = blockIdx.y;
    const int q0 = blockIdx.x * 32;
    const int kbeg = wv * KCHUNK;
    const _Float16* Q = qh + (size_t)combo * TT * DHV;
    const _Float16* K = kh + (size_t)combo * TT * DHV;
    const _Float16* V = vt + (size_t)combo * DHV * TT;

    // Q B-frags, held for the whole kernel
    f16x8 bq[2][2];
    #pragma unroll
    for (int qf = 0; qf < 2; ++qf)
        #pragma unroll
        for (int k0 = 0; k0 < 2; ++k0)
            bq[qf][k0] = *(const f16x8*)(Q + ((size_t)(q0 + qf * 16 + ln)) * DHV + k0 * 32 + g * 8);

    f32x4 O[4][2] = {};
    float mrun[2] = {-1e30f, -1e30f}, lrun[2] = {0.f, 0.f};

    // preload K frags for this wave's first tile
    f16x8 akc[4][2];
    #pragma unroll
    for (int m = 0; m < 4; ++m)
        #pragma unroll
        for (int k0 = 0; k0 < 2; ++k0)
            akc[m][k0] = *(const f16x8*)(K + ((size_t)(kbeg + m * 16 + ln)) * DHV + k0 * 32 + g * 8);

    for (int it = 0; it < KCHUNK / 64; ++it) {
        const int kb = kbeg + it * 64;
        const int kbn = (it + 1 < KCHUNK / 64) ? kb + 64 : kbeg;  // last-iter value unused

        // ---- issue V(kb) + K(next) loads NOW; consumed after softmax / next iter ----
        f16x8 av[4][2], akn[4][2];
        #pragma unroll
        for (int m = 0; m < 4; ++m)
            #pragma unroll
            for (int kc0 = 0; kc0 < 2; ++kc0)
                av[m][kc0] = *(const f16x8*)(V + ((size_t)(m * 16 + ln)) * TT + kb + kc0 * 32 + g * 8);
        #pragma unroll
        for (int m = 0; m < 4; ++m)
            #pragma unroll
            for (int k0 = 0; k0 < 2; ++k0)
                akn[m][k0] = *(const f16x8*)(K + ((size_t)(kbn + m * 16 + ln)) * DHV + k0 * 32 + g * 8);

        // ---- QK^T (swapped) on the K frags loaded last iteration ----
        f32x4 S[4][2] = {};
        #pragma unroll
        for (int m = 0; m < 4; ++m)
            #pragma unroll
            for (int qf = 0; qf < 2; ++qf) {
                S[m][qf] = __builtin_amdgcn_mfma_f32_16x16x32_f16(akc[m][0], bq[qf][0], S[m][qf], 0, 0, 0);
                S[m][qf] = __builtin_amdgcn_mfma_f32_16x16x32_f16(akc[m][1], bq[qf][1], S[m][qf], 0, 0, 0);
            }

        // ---- online softmax (rows lane-local; exp2 domain; tree reductions) ----
        #pragma unroll
        for (int qf = 0; qf < 2; ++qf) {
            float a0 = fmaxf(fmaxf(S[0][qf][0], S[0][qf][1]), fmaxf(S[0][qf][2], S[0][qf][3]));
            float a1 = fmaxf(fmaxf(S[1][qf][0], S[1][qf][1]), fmaxf(S[1][qf][2], S[1][qf][3]));
            float a2 = fmaxf(fmaxf(S[2][qf][0], S[2][qf][1]), fmaxf(S[2][qf][2], S[2][qf][3]));
            float a3 = fmaxf(fmaxf(S[3][qf][0], S[3][qf][1]), fmaxf(S[3][qf][2], S[3][qf][3]));
            float mx = fmaxf(fmaxf(a0, a1), fmaxf(a2, a3));
            mx = fmaxf(mx, __shfl_xor(mx, 16));
            mx = fmaxf(mx, __shfl_xor(mx, 32));
            const float mnew = fmaxf(mrun[qf], mx);
            const float corr = exp2f(mrun[qf] - mnew);
            float psm[4];
            #pragma unroll
            for (int m = 0; m < 4; ++m) {
                #pragma unroll
                for (int r = 0; r < 4; ++r)
                    S[m][qf][r] = exp2f(S[m][qf][r] - mnew);
                psm[m] = (S[m][qf][0] + S[m][qf][1]) + (S[m][qf][2] + S[m][qf][3]);
            }
            float ps = (psm[0] + psm[1]) + (psm[2] + psm[3]);
            ps += __shfl_xor(ps, 16);
            ps += __shfl_xor(ps, 32);
            lrun[qf] = lrun[qf] * corr + ps;
            mrun[qf] = mnew;
            #pragma unroll
            for (int m = 0; m < 4; ++m) O[m][qf] *= corr;
            #pragma unroll
            for (int m = 0; m < 4; ++m) {
                uint2 u;
                u.x = pk2(S[m][qf][0], S[m][qf][1]);
                u.y = pk2(S[m][qf][2], S[m][qf][3]);
                *(uint2*)&Plds[wv][qf * 16 + ln][m * 16 + g * 4] = u;
            }
        }

        // ---- PV (swapped): O^T += V^T_blk . P, V frags already in regs ----
        f16x8 bp[2][2];
        #pragma unroll
        for (int qf = 0; qf < 2; ++qf)
            #pragma unroll
            for (int kc0 = 0; kc0 < 2; ++kc0)
                bp[qf][kc0] = *(const f16x8*)&Plds[wv][qf * 16 + ln][kc0 * 32 + g * 8];
        #pragma unroll
        for (int m = 0; m < 4; ++m)
            #pragma unroll
            for (int kc0 = 0; kc0 < 2; ++kc0)
                #pragma unroll
                for (int qf = 0; qf < 2; ++qf)
                    O[m][qf] = __builtin_amdgcn_mfma_f32_16x16x32_f16(av[m][kc0], bp[qf][kc0], O[m][qf], 0, 0, 0);

        // rotate K prefetch regs
        #pragma unroll
        for (int m = 0; m < 4; ++m)
            #pragma unroll
            for (int k0 = 0; k0 < 2; ++k0)
                akc[m][k0] = akn[m][k0];
    }

    // ================= merge the 4 k-split partials =================
    __syncthreads();                       // all PV reads of Plds done
    if (g == 0) {
        #pragma unroll
        for (int qf = 0; qf < 2; ++qf) {
            mlbuf[wv][qf][ln][0] = mrun[qf];
            mlbuf[wv][qf][ln][1] = lrun[qf];
        }
    }
    __syncthreads();

    float Lfin[2];
    #pragma unroll
    for (int qf = 0; qf < 2; ++qf) {
        float m0 = mlbuf[0][qf][ln][0], m1 = mlbuf[1][qf][ln][0];
        float m2 = mlbuf[2][qf][ln][0], m3 = mlbuf[3][qf][ln][0];
        const float mstar = fmaxf(fmaxf(m0, m1), fmaxf(m2, m3));
        float L = mlbuf[0][qf][ln][1] * exp2f(m0 - mstar)
                + mlbuf[1][qf][ln][1] * exp2f(m1 - mstar)
                + mlbuf[2][qf][ln][1] * exp2f(m2 - mstar)
                + mlbuf[3][qf][ln][1] * exp2f(m3 - mstar);
        Lfin[qf] = L;
        const float sc = exp2f(mrun[qf] - mstar);
        #pragma unroll
        for (int m = 0; m < 4; ++m) O[m][qf] *= sc;
    }

    // tree-sum O across waves through Obuf (aliases Plds; safe after barrier)
    if (wv >= 2) {
        #pragma unroll
        for (int qf = 0; qf < 2; ++qf)
            #pragma unroll
            for (int m = 0; m < 4; ++m)
                *(f32x4*)&Obuf[wv - 2][qf * 16 + ln][m * 16 + g * 4] = O[m][qf];
    }
    __syncthreads();
    if (wv < 2) {
        #pragma unroll
        for (int qf = 0; qf < 2; ++qf)
            #pragma unroll
            for (int m = 0; m < 4; ++m)
                O[m][qf] += *(const f32x4*)&Obuf[wv][qf * 16 + ln][m * 16 + g * 4];
    }
    __syncthreads();
    if (wv == 1) {
        #pragma unroll
        for (int qf = 0; qf < 2; ++qf)
            #pragma unroll
            for (int m = 0; m < 4; ++m)
                *(f32x4*)&Obuf[0][qf * 16 + ln][m * 16 + g * 4] = O[m][qf];
    }
    __syncthreads();
    if (wv == 0) {
        const int s_ = combo >> 3, b_ = (combo >> 2) & 1, h_ = combo & 3;
        #pragma unroll
        for (int qf = 0; qf < 2; ++qf) {
            const float inv = 1.f / Lfin[qf];
            const int tok = q0 + qf * 16 + ln;
            #pragma unroll
            for (int m = 0; m < 4; ++m) {
                f32x4 ov = O[m][qf];
                ov += *(const f32x4*)&Obuf[0][qf * 16 + ln][m * 16 + g * 4];
                ov *= inv;
                *(f32x4*)&ocat[((size_t)(b_ * TT + tok)) * 1024 + s_ * 256 + h_ * 64 + m * 16 + g * 4] = ov;
            }
        }
    }
}

// ---------------------------------------------------------------------------
extern "C" void kernel_launch(void* const* d_in, const int* in_sizes, int n_in,
                              void* d_out, int out_size, void* d_ws, size_t ws_size,
                              hipStream_t stream)
{
    const float* x    = (const float*)d_in[0];
    const float* wci  = (const float*)d_in[1];
    const float* b1g  = (const float*)d_in[2];
    const float* b1b  = (const float*)d_in[3];
    const float* b1m  = (const float*)d_in[4];
    const float* b1v  = (const float*)d_in[5];
    const float* dww  = (const float*)d_in[6];
    const float* pww  = (const float*)d_in[7];
    const float* b2g  = (const float*)d_in[8];
    const float* b2b  = (const float*)d_in[9];
    const float* b2m  = (const float*)d_in[10];
    const float* b2v  = (const float*)d_in[11];
    const float* Wq   = (const float*)d_in[12];
    const float* Wk   = (const float*)d_in[13];
    const float* Wv   = (const float*)d_in[14];
    const float* Wout = (const float*)d_in[15];

    char* wsb = (char*)d_ws;
    float*     ident = (float*)(wsb + WSB_IDENT);
    float*     rt    = (float*)(wsb + WSB_RT);
    float*     dwt   = (float*)(wsb + WSB_DWT);
    float*     ysch  = (float*)(wsb + WSB_YS);
    _Float16*  qh    = (_Float16*)(wsb + WSB_QH);
    _Float16*  khp   = (_Float16*)(wsb + WSB_KH);
    _Float16*  vtp   = (_Float16*)(wsb + WSB_VT);
    float*     ocat  = (float*)(wsb + WSB_OCAT);
    float*     outp  = (float*)d_out;

    // 1) conv_in (1x1) + BN1
    gemm64<0><<<dim3(BB * TT / 64, CIN / 64), 256, 0, stream>>>(
        x, wci, nullptr, nullptr, ident, rt, nullptr, b1g, b1b, b1m, b1v, CIN, 0);

    // 2) Res2Net chain: dw3x3 -> pw 1x1 + BN2, scales 1..3 (sequential)
    for (int s = 1; s <= 3; ++s) {
        const float* yp = (s == 1) ? nullptr : (ysch + (size_t)(s - 2) * BB * C4 * TT);
        dw3x3<<<dim3(BB * C4 * TT / 256), 256, 0, stream>>>(ident, yp, dww, dwt, s);
        gemm64<1><<<dim3(BB * TT / 64, 1), 256, 0, stream>>>(
            dwt, pww, nullptr, nullptr, rt, ysch, nullptr, b2g, b2b, b2m, b2v, C4, s);
    }

    // 3) q/k/v projections -> f16 Q(log2e-scaled), K, V^T
    gemm64<2><<<dim3(4 * BB * TT / 64, CIN / 64, 3), 256, 0, stream>>>(
        rt, Wq, Wk, Wv, (float*)qh, (float*)khp, (float*)vtp,
        nullptr, nullptr, nullptr, nullptr, C4, 0);

    // 4) f16 MFMA flash attention (in-block k-split) -> o [B][T][1024] fp32
    attn_mfma<<<dim3(TT / 32, 32), 256, 0, stream>>>(qh, khp, vtp, ocat);

    // 5) output projection -> d_out
    gemm64<3><<<dim3(BB * TT / 64, CIN / 64), 256, 0, stream>>>(
        ocat, Wout, nullptr, nullptr, outp, nullptr, nullptr,
        nullptr, nullptr, nullptr, nullptr, 4 * CIN, 0);
}

// Round 10
// 314.184 us; speedup vs baseline: 2.5395x; 1.0058x over previous
//
#include <hip/hip_runtime.h>
#include <math.h>

#define BB 2
#define TT 2304
#define CIN 256
#define C4 64
#define NHEADS 4
#define DHV 64
#define HHH 48
#define WWW 48
#define EPSV 1e-5f
#define LOG2E 1.4426950408889634f
#define KSPLIT 4
#define KCHUNK (TT / KSPLIT)   // 576 keys = 9 tiles of 64 per wave

using f16x8 = __attribute__((ext_vector_type(8))) _Float16;
using f32x4 = __attribute__((ext_vector_type(4))) float;

// pack two f32 -> one u32 of two f16 (RTZ), type-safe via bit_cast
__device__ __forceinline__ unsigned pk2(float a, float b) {
    return __builtin_bit_cast(unsigned, __builtin_amdgcn_cvt_pkrtz(a, b));
}

// workspace layout (byte offsets)
#define WSB_IDENT 0u          // [BB][CIN][TT] f32      4718592
#define WSB_RT    4718592u    // [4][BB][TT][C4] f32    4718592
#define WSB_DWT   9437184u    // [C4][BB*TT] f32        1179648
#define WSB_YS    10616832u   // [3][BB][C4][TT] f32    3538944
#define WSB_QH    14155776u   // [32][TT][64] f16       9437184  (pre-scaled by log2e)
#define WSB_KH    23592960u   // [32][TT][64] f16       9437184
#define WSB_VT    33030144u   // [32][64][TT] f16       9437184  (V transposed)
#define WSB_OCAT  42467328u   // [BB][TT][1024] f32    18874368

// ---------------------------------------------------------------------------
// Generic 64x64-tile fp32 GEMM, A [M][K] row-major (or [K][M] col-major for
// MODE 1), W [N][K] row-major. 256 thr, 4x4/thread.
// MODE 0: conv_in + BN1 -> identity (ch-major) + r_t scale0 (tok-major)
// MODE 1: pointwise + BN2 -> r_t[scale] + ys_ch[scale-1]
// MODE 2: q/k/v projection (blockIdx.z selects W) -> f16 Q (log2e-scaled),
//         f16 K, f16 V^T
// MODE 3: output projection -> d_out
// ---------------------------------------------------------------------------
template<int MODE>
__global__ __launch_bounds__(256) void gemm64(
    const float* __restrict__ A,
    const float* __restrict__ W0, const float* __restrict__ W1, const float* __restrict__ W2,
    float* __restrict__ out, float* __restrict__ out2, float* __restrict__ out3,
    const float* __restrict__ bg, const float* __restrict__ bb,
    const float* __restrict__ bm, const float* __restrict__ bv,
    int Kdim, int scale_s)
{
    __shared__ __align__(16) float As[16][68];
    __shared__ __align__(16) float Ws[16][68];
    const int tid = threadIdx.x;
    const int m0 = blockIdx.x * 64;
    const int n0 = blockIdx.y * 64;
    const float* W = W0;
    if (MODE == 2) {
        if (blockIdx.z == 1) W = W1;
        else if (blockIdx.z == 2) W = W2;
    }
    const int tm = tid & 15, tn = tid >> 4;
    float acc[4][4] = {};
    for (int k0 = 0; k0 < Kdim; k0 += 16) {
        __syncthreads();
        if (MODE == 1) {
            const int kk = tid >> 4, mc = tid & 15;
            float4 a4 = *(const float4*)&A[(size_t)(k0 + kk) * (BB * TT) + m0 + mc * 4];
            *(float4*)&As[kk][mc * 4] = a4;
        } else {
            const int lr = tid >> 2, lc = tid & 3;
            float4 a4 = *(const float4*)&A[(size_t)(m0 + lr) * Kdim + k0 + lc * 4];
            As[lc * 4 + 0][lr] = a4.x; As[lc * 4 + 1][lr] = a4.y;
            As[lc * 4 + 2][lr] = a4.z; As[lc * 4 + 3][lr] = a4.w;
        }
        {
            const int lr = tid >> 2, lc = tid & 3;
            float4 w4 = *(const float4*)&W[(size_t)(n0 + lr) * Kdim + k0 + lc * 4];
            Ws[lc * 4 + 0][lr] = w4.x; Ws[lc * 4 + 1][lr] = w4.y;
            Ws[lc * 4 + 2][lr] = w4.z; Ws[lc * 4 + 3][lr] = w4.w;
        }
        __syncthreads();
        #pragma unroll
        for (int kk = 0; kk < 16; ++kk) {
            float4 af = *(const float4*)&As[kk][tm * 4];
            float4 wf = *(const float4*)&Ws[kk][tn * 4];
            float av[4] = {af.x, af.y, af.z, af.w};
            float wv[4] = {wf.x, wf.y, wf.z, wf.w};
            #pragma unroll
            for (int i = 0; i < 4; ++i)
                #pragma unroll
                for (int j = 0; j < 4; ++j)
                    acc[i][j] = fmaf(av[i], wv[j], acc[i][j]);
        }
    }

    if (MODE == 0) {
        #pragma unroll
        for (int j = 0; j < 4; ++j) {
            const int o = n0 + tn * 4 + j;
            const float inv = bg[o] * rsqrtf(bv[o] + EPSV);
            const float bet = bb[o] - bm[o] * inv;
            #pragma unroll
            for (int i = 0; i < 4; ++i) {
                const int m = m0 + tm * 4 + i;
                const int b = m / TT, t = m % TT;
                const float val = acc[i][j] * inv + bet;
                out[((size_t)(b * CIN + o)) * TT + t] = val;
                if (o < C4) out2[((size_t)(b * TT + t)) * C4 + o] = val;
            }
        }
    } else if (MODE == 1) {
        #pragma unroll
        for (int j = 0; j < 4; ++j) {
            const int o = n0 + tn * 4 + j;
            const float inv = bg[o] * rsqrtf(bv[o] + EPSV);
            const float bet = bb[o] - bm[o] * inv;
            #pragma unroll
            for (int i = 0; i < 4; ++i) {
                const int m = m0 + tm * 4 + i;
                const int b = m / TT, t = m % TT;
                const float val = acc[i][j] * inv + bet;
                out[(((size_t)scale_s * BB + b) * TT + t) * C4 + o] = val;
                out2[(((size_t)(scale_s - 1) * BB + b) * C4 + o) * TT + t] = val;
            }
        }
    } else if (MODE == 2) {
        const int z = blockIdx.z;
        const int h = n0 >> 6;
        #pragma unroll
        for (int i = 0; i < 4; ++i) {
            const int m = m0 + tm * 4 + i;
            const int s = m / (BB * TT);
            const int rem = m - s * (BB * TT);
            const int b = rem / TT, t = rem - (rem / TT) * TT;
            const int combo = (s * BB + b) * NHEADS + h;
            if (z == 0) {
                _Float16* dst = (_Float16*)out + ((size_t)combo * TT + t) * DHV + tn * 4;
                uint2 u;
                u.x = pk2(acc[i][0] * LOG2E, acc[i][1] * LOG2E);
                u.y = pk2(acc[i][2] * LOG2E, acc[i][3] * LOG2E);
                *(uint2*)dst = u;
            } else if (z == 1) {
                _Float16* dst = (_Float16*)out2 + ((size_t)combo * TT + t) * DHV + tn * 4;
                uint2 u;
                u.x = pk2(acc[i][0], acc[i][1]);
                u.y = pk2(acc[i][2], acc[i][3]);
                *(uint2*)dst = u;
            } else {
                _Float16* vtp = (_Float16*)out3;
                #pragma unroll
                for (int j = 0; j < 4; ++j)
                    vtp[((size_t)combo * DHV + tn * 4 + j) * TT + t] = (_Float16)acc[i][j];
            }
        }
    } else {
        #pragma unroll
        for (int i = 0; i < 4; ++i) {
            const int m = m0 + tm * 4 + i;
            float4 v4 = make_float4(acc[i][0], acc[i][1], acc[i][2], acc[i][3]);
            *(float4*)&out[(size_t)m * CIN + n0 + tn * 4] = v4;
        }
    }
}

// ---------------------------------------------------------------------------
// Depthwise 3x3 SAME, output col-major [C4][BB*TT].
// ---------------------------------------------------------------------------
__global__ __launch_bounds__(256) void dw3x3(
    const float* __restrict__ ident, const float* __restrict__ ysprev,
    const float* __restrict__ dww, float* __restrict__ dwt, int s)
{
    const int g = blockIdx.x * 256 + threadIdx.x;
    const int t = g % TT;
    const int c = (g / TT) & (C4 - 1);
    const int b = g / (TT * C4);
    const int h = t / WWW, w = t % WWW;
    const float* p1 = ident + ((size_t)(b * CIN + s * C4 + c)) * TT;
    const float* p2 = ysprev ? (ysprev + ((size_t)(b * C4 + c)) * TT) : nullptr;
    float acc = 0.f;
    #pragma unroll
    for (int kh = 0; kh < 3; ++kh) {
        const int hh2 = h + kh - 1;
        if (hh2 < 0 || hh2 >= HHH) continue;
        #pragma unroll
        for (int kw = 0; kw < 3; ++kw) {
            const int ww2 = w + kw - 1;
            if (ww2 < 0 || ww2 >= WWW) continue;
            const int t2 = hh2 * WWW + ww2;
            float v = p1[t2];
            if (p2) v += p2[t2];
            acc = fmaf(v, dww[c * 9 + kh * 3 + kw], acc);
        }
    }
    dwt[(size_t)c * (BB * TT) + b * TT + t] = acc;
}

// ---------------------------------------------------------------------------
// f16 MFMA flash attention, in-block k-split + XCD-affinity swizzle.
// 1D grid of 2304 blocks; assuming round-robin bid->XCD (bid&7), XCD x gets
// exactly combos 4x..4x+3 -> per-XCD K/V working set 2.35MB < 4MB L2, so
// K/V frag loads are L2-hits instead of L3 (~200 vs ~500 cyc).
// Block = 4 waves sharing ONE 32-row q-tile; wave w processes keys
// [w*576,(w+1)*576) with private online softmax; partials merge via LDS.
// An asm memory clobber after the V(kb)/K(next) load batch prevents the
// compiler from sinking those loads to their uses (round-9 failure mode:
// VGPR=64, pipeline discarded); launch_bounds(256,3) gives the allocator
// room (~168 VGPR cap) to keep the in-flight values.
// ---------------------------------------------------------------------------
__global__ __launch_bounds__(256, 3) void attn_mfma(
    const _Float16* __restrict__ qh, const _Float16* __restrict__ kh,
    const _Float16* __restrict__ vt, float* __restrict__ ocat)
{
    __shared__ __align__(16) char smemraw[22528];  // Plds [4][32][88]f16 / Obuf [2][32][68]f32
    __shared__ float mlbuf[KSPLIT][2][16][2];
    _Float16 (*Plds)[32][88] = (_Float16(*)[32][88])smemraw;
    float (*Obuf)[32][68] = (float(*)[32][68])smemraw;

    const int tid = threadIdx.x;
    const int wv = tid >> 6;
    const int lane = tid & 63;
    const int g = lane >> 4, ln = lane & 15;
    // XCD-affinity decode: xcd = bid&7 owns combos 4*xcd..4*xcd+3
    const int bid = blockIdx.x;
    const int xcd = bid & 7, slot = bid >> 3;      // slot in 0..287
    const int combo = (xcd << 2) | (slot / 72);
    const int q0 = (slot % 72) * 32;
    const int kbeg = wv * KCHUNK;
    const _Float16* Q = qh + (size_t)combo * TT * DHV;
    const _Float16* K = kh + (size_t)combo * TT * DHV;
    const _Float16* V = vt + (size_t)combo * DHV * TT;

    // Q B-frags, held for the whole kernel
    f16x8 bq[2][2];
    #pragma unroll
    for (int qf = 0; qf < 2; ++qf)
        #pragma unroll
        for (int k0 = 0; k0 < 2; ++k0)
            bq[qf][k0] = *(const f16x8*)(Q + ((size_t)(q0 + qf * 16 + ln)) * DHV + k0 * 32 + g * 8);

    f32x4 O[4][2] = {};
    float mrun[2] = {-1e30f, -1e30f}, lrun[2] = {0.f, 0.f};

    // preload K frags for this wave's first tile
    f16x8 akc[4][2];
    #pragma unroll
    for (int m = 0; m < 4; ++m)
        #pragma unroll
        for (int k0 = 0; k0 < 2; ++k0)
            akc[m][k0] = *(const f16x8*)(K + ((size_t)(kbeg + m * 16 + ln)) * DHV + k0 * 32 + g * 8);

    for (int it = 0; it < KCHUNK / 64; ++it) {
        const int kb = kbeg + it * 64;
        const int kbn = (it + 1 < KCHUNK / 64) ? kb + 64 : kbeg;  // last-iter value unused

        // ---- issue V(kb) + K(next) loads NOW; consumed after softmax / next iter ----
        f16x8 av[4][2], akn[4][2];
        #pragma unroll
        for (int m = 0; m < 4; ++m)
            #pragma unroll
            for (int kc0 = 0; kc0 < 2; ++kc0)
                av[m][kc0] = *(const f16x8*)(V + ((size_t)(m * 16 + ln)) * TT + kb + kc0 * 32 + g * 8);
        #pragma unroll
        for (int m = 0; m < 4; ++m)
            #pragma unroll
            for (int k0 = 0; k0 < 2; ++k0)
                akn[m][k0] = *(const f16x8*)(K + ((size_t)(kbn + m * 16 + ln)) * DHV + k0 * 32 + g * 8);
        // loads may not sink below this point (memory clobber)
        asm volatile("" ::: "memory");

        // ---- QK^T (swapped) on the K frags loaded last iteration ----
        f32x4 S[4][2] = {};
        #pragma unroll
        for (int m = 0; m < 4; ++m)
            #pragma unroll
            for (int qf = 0; qf < 2; ++qf) {
                S[m][qf] = __builtin_amdgcn_mfma_f32_16x16x32_f16(akc[m][0], bq[qf][0], S[m][qf], 0, 0, 0);
                S[m][qf] = __builtin_amdgcn_mfma_f32_16x16x32_f16(akc[m][1], bq[qf][1], S[m][qf], 0, 0, 0);
            }

        // ---- online softmax (rows lane-local; exp2 domain; tree reductions) ----
        #pragma unroll
        for (int qf = 0; qf < 2; ++qf) {
            float a0 = fmaxf(fmaxf(S[0][qf][0], S[0][qf][1]), fmaxf(S[0][qf][2], S[0][qf][3]));
            float a1 = fmaxf(fmaxf(S[1][qf][0], S[1][qf][1]), fmaxf(S[1][qf][2], S[1][qf][3]));
            float a2 = fmaxf(fmaxf(S[2][qf][0], S[2][qf][1]), fmaxf(S[2][qf][2], S[2][qf][3]));
            float a3 = fmaxf(fmaxf(S[3][qf][0], S[3][qf][1]), fmaxf(S[3][qf][2], S[3][qf][3]));
            float mx = fmaxf(fmaxf(a0, a1), fmaxf(a2, a3));
            mx = fmaxf(mx, __shfl_xor(mx, 16));
            mx = fmaxf(mx, __shfl_xor(mx, 32));
            const float mnew = fmaxf(mrun[qf], mx);
            const float corr = exp2f(mrun[qf] - mnew);
            float psm[4];
            #pragma unroll
            for (int m = 0; m < 4; ++m) {
                #pragma unroll
                for (int r = 0; r < 4; ++r)
                    S[m][qf][r] = exp2f(S[m][qf][r] - mnew);
                psm[m] = (S[m][qf][0] + S[m][qf][1]) + (S[m][qf][2] + S[m][qf][3]);
            }
            float ps = (psm[0] + psm[1]) + (psm[2] + psm[3]);
            ps += __shfl_xor(ps, 16);
            ps += __shfl_xor(ps, 32);
            lrun[qf] = lrun[qf] * corr + ps;
            mrun[qf] = mnew;
            #pragma unroll
            for (int m = 0; m < 4; ++m) O[m][qf] *= corr;
            #pragma unroll
            for (int m = 0; m < 4; ++m) {
                uint2 u;
                u.x = pk2(S[m][qf][0], S[m][qf][1]);
                u.y = pk2(S[m][qf][2], S[m][qf][3]);
                *(uint2*)&Plds[wv][qf * 16 + ln][m * 16 + g * 4] = u;
            }
        }

        // ---- PV (swapped): O^T += V^T_blk . P, V frags already in regs ----
        f16x8 bp[2][2];
        #pragma unroll
        for (int qf = 0; qf < 2; ++qf)
            #pragma unroll
            for (int kc0 = 0; kc0 < 2; ++kc0)
                bp[qf][kc0] = *(const f16x8*)&Plds[wv][qf * 16 + ln][kc0 * 32 + g * 8];
        #pragma unroll
        for (int m = 0; m < 4; ++m)
            #pragma unroll
            for (int kc0 = 0; kc0 < 2; ++kc0)
                #pragma unroll
                for (int qf = 0; qf < 2; ++qf)
                    O[m][qf] = __builtin_amdgcn_mfma_f32_16x16x32_f16(av[m][kc0], bp[qf][kc0], O[m][qf], 0, 0, 0);

        // rotate K prefetch regs
        #pragma unroll
        for (int m = 0; m < 4; ++m)
            #pragma unroll
            for (int k0 = 0; k0 < 2; ++k0)
                akc[m][k0] = akn[m][k0];
    }

    // ================= merge the 4 k-split partials =================
    __syncthreads();                       // all PV reads of Plds done
    if (g == 0) {
        #pragma unroll
        for (int qf = 0; qf < 2; ++qf) {
            mlbuf[wv][qf][ln][0] = mrun[qf];
            mlbuf[wv][qf][ln][1] = lrun[qf];
        }
    }
    __syncthreads();

    float Lfin[2];
    #pragma unroll
    for (int qf = 0; qf < 2; ++qf) {
        float m0 = mlbuf[0][qf][ln][0], m1 = mlbuf[1][qf][ln][0];
        float m2 = mlbuf[2][qf][ln][0], m3 = mlbuf[3][qf][ln][0];
        const float mstar = fmaxf(fmaxf(m0, m1), fmaxf(m2, m3));
        float L = mlbuf[0][qf][ln][1] * exp2f(m0 - mstar)
                + mlbuf[1][qf][ln][1] * exp2f(m1 - mstar)
                + mlbuf[2][qf][ln][1] * exp2f(m2 - mstar)
                + mlbuf[3][qf][ln][1] * exp2f(m3 - mstar);
        Lfin[qf] = L;
        const float sc = exp2f(mrun[qf] - mstar);
        #pragma unroll
        for (int m = 0; m < 4; ++m) O[m][qf] *= sc;
    }

    // tree-sum O across waves through Obuf (aliases Plds; safe after barrier)
    if (wv >= 2) {
        #pragma unroll
        for (int qf = 0; qf < 2; ++qf)
            #pragma unroll
            for (int m = 0; m < 4; ++m)
                *(f32x4*)&Obuf[wv - 2][qf * 16 + ln][m * 16 + g * 4] = O[m][qf];
    }
    __syncthreads();
    if (wv < 2) {
        #pragma unroll
        for (int qf = 0; qf < 2; ++qf)
            #pragma unroll
            for (int m = 0; m < 4; ++m)
                O[m][qf] += *(const f32x4*)&Obuf[wv][qf * 16 + ln][m * 16 + g * 4];
    }
    __syncthreads();
    if (wv == 1) {
        #pragma unroll
        for (int qf = 0; qf < 2; ++qf)
            #pragma unroll
            for (int m = 0; m < 4; ++m)
                *(f32x4*)&Obuf[0][qf * 16 + ln][m * 16 + g * 4] = O[m][qf];
    }
    __syncthreads();
    if (wv == 0) {
        const int s_ = combo >> 3, b_ = (combo >> 2) & 1, h_ = combo & 3;
        #pragma unroll
        for (int qf = 0; qf < 2; ++qf) {
            const float inv = 1.f / Lfin[qf];
            const int tok = q0 + qf * 16 + ln;
            #pragma unroll
            for (int m = 0; m < 4; ++m) {
                f32x4 ov = O[m][qf];
                ov += *(const f32x4*)&Obuf[0][qf * 16 + ln][m * 16 + g * 4];
                ov *= inv;
                *(f32x4*)&ocat[((size_t)(b_ * TT + tok)) * 1024 + s_ * 256 + h_ * 64 + m * 16 + g * 4] = ov;
            }
        }
    }
}

// ---------------------------------------------------------------------------
extern "C" void kernel_launch(void* const* d_in, const int* in_sizes, int n_in,
                              void* d_out, int out_size, void* d_ws, size_t ws_size,
                              hipStream_t stream)
{
    const float* x    = (const float*)d_in[0];
    const float* wci  = (const float*)d_in[1];
    const float* b1g  = (const float*)d_in[2];
    const float* b1b  = (const float*)d_in[3];
    const float* b1m  = (const float*)d_in[4];
    const float* b1v  = (const float*)d_in[5];
    const float* dww  = (const float*)d_in[6];
    const float* pww  = (const float*)d_in[7];
    const float* b2g  = (const float*)d_in[8];
    const float* b2b  = (const float*)d_in[9];
    const float* b2m  = (const float*)d_in[10];
    const float* b2v  = (const float*)d_in[11];
    const float* Wq   = (const float*)d_in[12];
    const float* Wk   = (const float*)d_in[13];
    const float* Wv   = (const float*)d_in[14];
    const float* Wout = (const float*)d_in[15];

    char* wsb = (char*)d_ws;
    float*     ident = (float*)(wsb + WSB_IDENT);
    float*     rt    = (float*)(wsb + WSB_RT);
    float*     dwt   = (float*)(wsb + WSB_DWT);
    float*     ysch  = (float*)(wsb + WSB_YS);
    _Float16*  qh    = (_Float16*)(wsb + WSB_QH);
    _Float16*  khp   = (_Float16*)(wsb + WSB_KH);
    _Float16*  vtp   = (_Float16*)(wsb + WSB_VT);
    float*     ocat  = (float*)(wsb + WSB_OCAT);
    float*     outp  = (float*)d_out;

    // 1) conv_in (1x1) + BN1
    gemm64<0><<<dim3(BB * TT / 64, CIN / 64), 256, 0, stream>>>(
        x, wci, nullptr, nullptr, ident, rt, nullptr, b1g, b1b, b1m, b1v, CIN, 0);

    // 2) Res2Net chain: dw3x3 -> pw 1x1 + BN2, scales 1..3 (sequential)
    for (int s = 1; s <= 3; ++s) {
        const float* yp = (s == 1) ? nullptr : (ysch + (size_t)(s - 2) * BB * C4 * TT);
        dw3x3<<<dim3(BB * C4 * TT / 256), 256, 0, stream>>>(ident, yp, dww, dwt, s);
        gemm64<1><<<dim3(BB * TT / 64, 1), 256, 0, stream>>>(
            dwt, pww, nullptr, nullptr, rt, ysch, nullptr, b2g, b2b, b2m, b2v, C4, s);
    }

    // 3) q/k/v projections -> f16 Q(log2e-scaled), K, V^T
    gemm64<2><<<dim3(4 * BB * TT / 64, CIN / 64, 3), 256, 0, stream>>>(
        rt, Wq, Wk, Wv, (float*)qh, (float*)khp, (float*)vtp,
        nullptr, nullptr, nullptr, nullptr, C4, 0);

    // 4) f16 MFMA flash attention (k-split + XCD swizzle) -> o [B][T][1024]
    attn_mfma<<<dim3(TT / 32 * 32), 256, 0, stream>>>(qh, khp, vtp, ocat);

    // 5) output projection -> d_out
    gemm64<3><<<dim3(BB * TT / 64, CIN / 64), 256, 0, stream>>>(
        ocat, Wout, nullptr, nullptr, outp, nullptr, nullptr,
        nullptr, nullptr, nullptr, nullptr, 4 * CIN, 0);
}

// Round 11
// 277.267 us; speedup vs baseline: 2.8776x; 1.1331x over previous
//
#include <hip/hip_runtime.h>
#include <math.h>

#define BB 2
#define TT 2304
#define CIN 256
#define C4 64
#define NHEADS 4
#define DHV 64
#define HHH 48
#define WWW 48
#define EPSV 1e-5f
#define LOG2E 1.4426950408889634f
#define KSPLIT 4
#define KCHUNK (TT / KSPLIT)   // 576 keys = 9 tiles of 64 per wave

using f16x8 = __attribute__((ext_vector_type(8))) _Float16;
using f32x4 = __attribute__((ext_vector_type(4))) float;

// pack two f32 -> one u32 of two f16 (RTZ), type-safe via bit_cast
__device__ __forceinline__ unsigned pk2(float a, float b) {
    return __builtin_bit_cast(unsigned, __builtin_amdgcn_cvt_pkrtz(a, b));
}

// workspace layout (byte offsets)
#define WSB_IDENT 0u          // [BB][CIN][TT] f32      4718592
#define WSB_RT16  4718592u    // [4][BB][TT][64] f16    2359296
#define WSB_DWT   7077888u    // [C4][BB*TT] f32        1179648
#define WSB_YS    8257536u    // [3][BB][C4][TT] f32    3538944
#define WSB_QH    11796480u   // [32][TT][64] f16       9437184  (log2e-scaled)
#define WSB_KH    21233664u   // [32][TT][64] f16       9437184
#define WSB_VT    30670848u   // [32][64][TT] f16       9437184  (V transposed)
#define WSB_OC16  40108032u   // [BB][TT][1024] f16     9437184
#define WSB_W16   49545216u   // wq,wk,wv (3x16384) + wout (262144) f16

// ---------------------------------------------------------------------------
// Weight conversion f32 -> f16: wq,wk,wv (16384 each), wout (262144).
// 38912 x 8-elem units = 152 blocks x 256 threads exactly.
// ---------------------------------------------------------------------------
__global__ __launch_bounds__(256) void wcvt(
    const float* __restrict__ s0, const float* __restrict__ s1,
    const float* __restrict__ s2, const float* __restrict__ s3,
    _Float16* __restrict__ w16)
{
    const int i = blockIdx.x * 256 + threadIdx.x;
    const float* s; _Float16* d; int off;
    if (i < 2048)      { s = s0; d = w16;          off = i; }
    else if (i < 4096) { s = s1; d = w16 + 16384;  off = i - 2048; }
    else if (i < 6144) { s = s2; d = w16 + 32768;  off = i - 4096; }
    else               { s = s3; d = w16 + 49152;  off = i - 6144; }
    float4 a = ((const float4*)s)[off * 2];
    float4 b = ((const float4*)s)[off * 2 + 1];
    uint4 u;
    u.x = pk2(a.x, a.y); u.y = pk2(a.z, a.w);
    u.z = pk2(b.x, b.y); u.w = pk2(b.z, b.w);
    ((uint4*)d)[off] = u;
}

// ---------------------------------------------------------------------------
// fp32 64x64-tile GEMM (kept for conv_in and pointwise; both feed convs).
// MODE 0: conv_in + BN1 -> identity (ch-major f32) + rt16 scale0 (f16)
// MODE 1: pointwise + BN2 -> rt16[scale] (f16) + ys_ch[scale-1] (f32)
// ---------------------------------------------------------------------------
template<int MODE>
__global__ __launch_bounds__(256) void gemm64(
    const float* __restrict__ A, const float* __restrict__ W,
    float* __restrict__ out, float* __restrict__ out2,
    const float* __restrict__ bg, const float* __restrict__ bb,
    const float* __restrict__ bm, const float* __restrict__ bv,
    int Kdim, int scale_s)
{
    __shared__ __align__(16) float As[16][68];
    __shared__ __align__(16) float Ws[16][68];
    const int tid = threadIdx.x;
    const int m0 = blockIdx.x * 64;
    const int n0 = blockIdx.y * 64;
    const int tm = tid & 15, tn = tid >> 4;
    float acc[4][4] = {};
    for (int k0 = 0; k0 < Kdim; k0 += 16) {
        __syncthreads();
        if (MODE == 1) {
            const int kk = tid >> 4, mc = tid & 15;
            float4 a4 = *(const float4*)&A[(size_t)(k0 + kk) * (BB * TT) + m0 + mc * 4];
            *(float4*)&As[kk][mc * 4] = a4;
        } else {
            const int lr = tid >> 2, lc = tid & 3;
            float4 a4 = *(const float4*)&A[(size_t)(m0 + lr) * Kdim + k0 + lc * 4];
            As[lc * 4 + 0][lr] = a4.x; As[lc * 4 + 1][lr] = a4.y;
            As[lc * 4 + 2][lr] = a4.z; As[lc * 4 + 3][lr] = a4.w;
        }
        {
            const int lr = tid >> 2, lc = tid & 3;
            float4 w4 = *(const float4*)&W[(size_t)(n0 + lr) * Kdim + k0 + lc * 4];
            Ws[lc * 4 + 0][lr] = w4.x; Ws[lc * 4 + 1][lr] = w4.y;
            Ws[lc * 4 + 2][lr] = w4.z; Ws[lc * 4 + 3][lr] = w4.w;
        }
        __syncthreads();
        #pragma unroll
        for (int kk = 0; kk < 16; ++kk) {
            float4 af = *(const float4*)&As[kk][tm * 4];
            float4 wf = *(const float4*)&Ws[kk][tn * 4];
            float av[4] = {af.x, af.y, af.z, af.w};
            float wv[4] = {wf.x, wf.y, wf.z, wf.w};
            #pragma unroll
            for (int i = 0; i < 4; ++i)
                #pragma unroll
                for (int j = 0; j < 4; ++j)
                    acc[i][j] = fmaf(av[i], wv[j], acc[i][j]);
        }
    }

    if (MODE == 0) {
        _Float16* rt16 = (_Float16*)out2;
        #pragma unroll
        for (int j = 0; j < 4; ++j) {
            const int o = n0 + tn * 4 + j;
            const float inv = bg[o] * rsqrtf(bv[o] + EPSV);
            const float bet = bb[o] - bm[o] * inv;
            #pragma unroll
            for (int i = 0; i < 4; ++i) {
                const int m = m0 + tm * 4 + i;
                const int b = m / TT, t = m % TT;
                const float val = acc[i][j] * inv + bet;
                out[((size_t)(b * CIN + o)) * TT + t] = val;
                if (o < C4) rt16[((size_t)(b * TT + t)) * C4 + o] = (_Float16)val;
            }
        }
    } else {
        _Float16* rt16 = (_Float16*)out;
        #pragma unroll
        for (int j = 0; j < 4; ++j) {
            const int o = n0 + tn * 4 + j;
            const float inv = bg[o] * rsqrtf(bv[o] + EPSV);
            const float bet = bb[o] - bm[o] * inv;
            #pragma unroll
            for (int i = 0; i < 4; ++i) {
                const int m = m0 + tm * 4 + i;
                const int b = m / TT, t = m % TT;
                const float val = acc[i][j] * inv + bet;
                rt16[(((size_t)scale_s * BB + b) * TT + t) * C4 + o] = (_Float16)val;
                out2[(((size_t)(scale_s - 1) * BB + b) * C4 + o) * TT + t] = val;
            }
        }
    }
}

// ---------------------------------------------------------------------------
// Depthwise 3x3 SAME, output col-major [C4][BB*TT].
// ---------------------------------------------------------------------------
__global__ __launch_bounds__(256) void dw3x3(
    const float* __restrict__ ident, const float* __restrict__ ysprev,
    const float* __restrict__ dww, float* __restrict__ dwt, int s)
{
    const int g = blockIdx.x * 256 + threadIdx.x;
    const int t = g % TT;
    const int c = (g / TT) & (C4 - 1);
    const int b = g / (TT * C4);
    const int h = t / WWW, w = t % WWW;
    const float* p1 = ident + ((size_t)(b * CIN + s * C4 + c)) * TT;
    const float* p2 = ysprev ? (ysprev + ((size_t)(b * C4 + c)) * TT) : nullptr;
    float acc = 0.f;
    #pragma unroll
    for (int kh = 0; kh < 3; ++kh) {
        const int hh2 = h + kh - 1;
        if (hh2 < 0 || hh2 >= HHH) continue;
        #pragma unroll
        for (int kw = 0; kw < 3; ++kw) {
            const int ww2 = w + kw - 1;
            if (ww2 < 0 || ww2 >= WWW) continue;
            const int t2 = hh2 * WWW + ww2;
            float v = p1[t2];
            if (p2) v += p2[t2];
            acc = fmaf(v, dww[c * 9 + kh * 3 + kw], acc);
        }
    }
    dwt[(size_t)c * (BB * TT) + b * TT + t] = acc;
}

// ---------------------------------------------------------------------------
// q/k/v projection, f16 MFMA, K=64 (2 k-steps). grid (144, 8, 3), 4 waves.
// Wave computes a 32m x 32o tile. D-lane map: col=ln (B row), row=g*4+r (A row).
// z=0/1 (q,k): A=rt16 rows (t), B=W rows (o) -> D[t][o]; q scaled by LOG2E.
// z=2 (v):     A=W rows (o),   B=rt16 rows (t) -> D[o][t] = V^T directly.
// ---------------------------------------------------------------------------
__global__ __launch_bounds__(256) void qkv_mfma(
    const _Float16* __restrict__ rt16, const _Float16* __restrict__ w16,
    _Float16* __restrict__ qh, _Float16* __restrict__ kh, _Float16* __restrict__ vt)
{
    const int tid = threadIdx.x;
    const int wv = tid >> 6;
    const int lane = tid & 63;
    const int g = lane >> 4, ln = lane & 15;
    const int z = blockIdx.z;
    const _Float16* W = w16 + z * 16384;
    const int m0 = blockIdx.x * 128 + wv * 32;   // 18432 rows total, one (s,b) per block
    const int o0 = blockIdx.y * 32;
    const int s = m0 / (BB * TT);
    const int rem = m0 - s * (BB * TT);
    const int b = rem / TT;
    const int t0 = rem - b * TT;
    const int h = o0 >> 6;
    const int dbase = (o0 & 63);
    const int combo = (s * BB + b) * NHEADS + h;

    if (z < 2) {
        f16x8 a[2][2], bf[2][2];
        #pragma unroll
        for (int mi = 0; mi < 2; ++mi)
            #pragma unroll
            for (int ks = 0; ks < 2; ++ks)
                a[mi][ks] = *(const f16x8*)(rt16 + ((size_t)(m0 + mi * 16 + ln)) * 64 + ks * 32 + g * 8);
        #pragma unroll
        for (int oi = 0; oi < 2; ++oi)
            #pragma unroll
            for (int ks = 0; ks < 2; ++ks)
                bf[oi][ks] = *(const f16x8*)(W + ((size_t)(o0 + oi * 16 + ln)) * 64 + ks * 32 + g * 8);
        f32x4 acc[2][2] = {};
        #pragma unroll
        for (int ks = 0; ks < 2; ++ks)
            #pragma unroll
            for (int mi = 0; mi < 2; ++mi)
                #pragma unroll
                for (int oi = 0; oi < 2; ++oi)
                    acc[mi][oi] = __builtin_amdgcn_mfma_f32_16x16x32_f16(a[mi][ks], bf[oi][ks], acc[mi][oi], 0, 0, 0);
        _Float16* dst = (z == 0) ? qh : kh;
        const float sc = (z == 0) ? LOG2E : 1.f;
        #pragma unroll
        for (int mi = 0; mi < 2; ++mi)
            #pragma unroll
            for (int oi = 0; oi < 2; ++oi) {
                const int d = dbase + oi * 16 + ln;
                #pragma unroll
                for (int r = 0; r < 4; ++r) {
                    const int t = t0 + mi * 16 + g * 4 + r;
                    dst[((size_t)combo * TT + t) * DHV + d] = (_Float16)(acc[mi][oi][r] * sc);
                }
            }
    } else {
        f16x8 a[2][2], bf[2][2];
        #pragma unroll
        for (int oi = 0; oi < 2; ++oi)
            #pragma unroll
            for (int ks = 0; ks < 2; ++ks)
                a[oi][ks] = *(const f16x8*)(W + ((size_t)(o0 + oi * 16 + ln)) * 64 + ks * 32 + g * 8);
        #pragma unroll
        for (int ti = 0; ti < 2; ++ti)
            #pragma unroll
            for (int ks = 0; ks < 2; ++ks)
                bf[ti][ks] = *(const f16x8*)(rt16 + ((size_t)(m0 + ti * 16 + ln)) * 64 + ks * 32 + g * 8);
        f32x4 acc[2][2] = {};
        #pragma unroll
        for (int ks = 0; ks < 2; ++ks)
            #pragma unroll
            for (int oi = 0; oi < 2; ++oi)
                #pragma unroll
                for (int ti = 0; ti < 2; ++ti)
                    acc[oi][ti] = __builtin_amdgcn_mfma_f32_16x16x32_f16(a[oi][ks], bf[ti][ks], acc[oi][ti], 0, 0, 0);
        #pragma unroll
        for (int oi = 0; oi < 2; ++oi)
            #pragma unroll
            for (int ti = 0; ti < 2; ++ti) {
                const int t = t0 + ti * 16 + ln;
                #pragma unroll
                for (int r = 0; r < 4; ++r) {
                    const int d = dbase + oi * 16 + g * 4 + r;
                    vt[((size_t)combo * DHV + d) * TT + t] = (_Float16)acc[oi][ti][r];
                }
            }
    }
}

// ---------------------------------------------------------------------------
// Output projection, f16 MFMA: [4608,1024] x [256,1024]^T -> d_out f32.
// grid (72, 8), 4 waves; wave = 16m x 32o, K-loop 32 steps of 32.
// ---------------------------------------------------------------------------
__global__ __launch_bounds__(256) void out_mfma(
    const _Float16* __restrict__ oc16, const _Float16* __restrict__ wout16,
    float* __restrict__ out)
{
    const int tid = threadIdx.x;
    const int wv = tid >> 6;
    const int lane = tid & 63;
    const int g = lane >> 4, ln = lane & 15;
    const int m0 = blockIdx.x * 64 + wv * 16;
    const int o0 = blockIdx.y * 32;
    f32x4 acc[2] = {};
    for (int k0 = 0; k0 < 1024; k0 += 32) {
        f16x8 a = *(const f16x8*)(oc16 + ((size_t)(m0 + ln)) * 1024 + k0 + g * 8);
        #pragma unroll
        for (int oi = 0; oi < 2; ++oi) {
            f16x8 bf = *(const f16x8*)(wout16 + ((size_t)(o0 + oi * 16 + ln)) * 1024 + k0 + g * 8);
            acc[oi] = __builtin_amdgcn_mfma_f32_16x16x32_f16(a, bf, acc[oi], 0, 0, 0);
        }
    }
    #pragma unroll
    for (int oi = 0; oi < 2; ++oi)
        #pragma unroll
        for (int r = 0; r < 4; ++r)
            out[((size_t)(m0 + g * 4 + r)) * CIN + o0 + oi * 16 + ln] = acc[oi][r];
}

// ---------------------------------------------------------------------------
// f16 MFMA flash attention (unchanged from round 10, except f16 ocat output).
// In-block k-split(4) + XCD-affinity swizzle; partials merge via LDS.
// ---------------------------------------------------------------------------
__global__ __launch_bounds__(256, 3) void attn_mfma(
    const _Float16* __restrict__ qh, const _Float16* __restrict__ kh,
    const _Float16* __restrict__ vt, _Float16* __restrict__ oc16)
{
    __shared__ __align__(16) char smemraw[22528];  // Plds [4][32][88]f16 / Obuf [2][32][68]f32
    __shared__ float mlbuf[KSPLIT][2][16][2];
    _Float16 (*Plds)[32][88] = (_Float16(*)[32][88])smemraw;
    float (*Obuf)[32][68] = (float(*)[32][68])smemraw;

    const int tid = threadIdx.x;
    const int wv = tid >> 6;
    const int lane = tid & 63;
    const int g = lane >> 4, ln = lane & 15;
    const int bid = blockIdx.x;
    const int xcd = bid & 7, slot = bid >> 3;
    const int combo = (xcd << 2) | (slot / 72);
    const int q0 = (slot % 72) * 32;
    const int kbeg = wv * KCHUNK;
    const _Float16* Q = qh + (size_t)combo * TT * DHV;
    const _Float16* K = kh + (size_t)combo * TT * DHV;
    const _Float16* V = vt + (size_t)combo * DHV * TT;

    f16x8 bq[2][2];
    #pragma unroll
    for (int qf = 0; qf < 2; ++qf)
        #pragma unroll
        for (int k0 = 0; k0 < 2; ++k0)
            bq[qf][k0] = *(const f16x8*)(Q + ((size_t)(q0 + qf * 16 + ln)) * DHV + k0 * 32 + g * 8);

    f32x4 O[4][2] = {};
    float mrun[2] = {-1e30f, -1e30f}, lrun[2] = {0.f, 0.f};

    f16x8 akc[4][2];
    #pragma unroll
    for (int m = 0; m < 4; ++m)
        #pragma unroll
        for (int k0 = 0; k0 < 2; ++k0)
            akc[m][k0] = *(const f16x8*)(K + ((size_t)(kbeg + m * 16 + ln)) * DHV + k0 * 32 + g * 8);

    for (int it = 0; it < KCHUNK / 64; ++it) {
        const int kb = kbeg + it * 64;
        const int kbn = (it + 1 < KCHUNK / 64) ? kb + 64 : kbeg;

        f16x8 av[4][2], akn[4][2];
        #pragma unroll
        for (int m = 0; m < 4; ++m)
            #pragma unroll
            for (int kc0 = 0; kc0 < 2; ++kc0)
                av[m][kc0] = *(const f16x8*)(V + ((size_t)(m * 16 + ln)) * TT + kb + kc0 * 32 + g * 8);
        #pragma unroll
        for (int m = 0; m < 4; ++m)
            #pragma unroll
            for (int k0 = 0; k0 < 2; ++k0)
                akn[m][k0] = *(const f16x8*)(K + ((size_t)(kbn + m * 16 + ln)) * DHV + k0 * 32 + g * 8);
        asm volatile("" ::: "memory");

        f32x4 S[4][2] = {};
        #pragma unroll
        for (int m = 0; m < 4; ++m)
            #pragma unroll
            for (int qf = 0; qf < 2; ++qf) {
                S[m][qf] = __builtin_amdgcn_mfma_f32_16x16x32_f16(akc[m][0], bq[qf][0], S[m][qf], 0, 0, 0);
                S[m][qf] = __builtin_amdgcn_mfma_f32_16x16x32_f16(akc[m][1], bq[qf][1], S[m][qf], 0, 0, 0);
            }

        #pragma unroll
        for (int qf = 0; qf < 2; ++qf) {
            float a0 = fmaxf(fmaxf(S[0][qf][0], S[0][qf][1]), fmaxf(S[0][qf][2], S[0][qf][3]));
            float a1 = fmaxf(fmaxf(S[1][qf][0], S[1][qf][1]), fmaxf(S[1][qf][2], S[1][qf][3]));
            float a2 = fmaxf(fmaxf(S[2][qf][0], S[2][qf][1]), fmaxf(S[2][qf][2], S[2][qf][3]));
            float a3 = fmaxf(fmaxf(S[3][qf][0], S[3][qf][1]), fmaxf(S[3][qf][2], S[3][qf][3]));
            float mx = fmaxf(fmaxf(a0, a1), fmaxf(a2, a3));
            mx = fmaxf(mx, __shfl_xor(mx, 16));
            mx = fmaxf(mx, __shfl_xor(mx, 32));
            const float mnew = fmaxf(mrun[qf], mx);
            const float corr = exp2f(mrun[qf] - mnew);
            float psm[4];
            #pragma unroll
            for (int m = 0; m < 4; ++m) {
                #pragma unroll
                for (int r = 0; r < 4; ++r)
                    S[m][qf][r] = exp2f(S[m][qf][r] - mnew);
                psm[m] = (S[m][qf][0] + S[m][qf][1]) + (S[m][qf][2] + S[m][qf][3]);
            }
            float ps = (psm[0] + psm[1]) + (psm[2] + psm[3]);
            ps += __shfl_xor(ps, 16);
            ps += __shfl_xor(ps, 32);
            lrun[qf] = lrun[qf] * corr + ps;
            mrun[qf] = mnew;
            #pragma unroll
            for (int m = 0; m < 4; ++m) O[m][qf] *= corr;
            #pragma unroll
            for (int m = 0; m < 4; ++m) {
                uint2 u;
                u.x = pk2(S[m][qf][0], S[m][qf][1]);
                u.y = pk2(S[m][qf][2], S[m][qf][3]);
                *(uint2*)&Plds[wv][qf * 16 + ln][m * 16 + g * 4] = u;
            }
        }

        f16x8 bp[2][2];
        #pragma unroll
        for (int qf = 0; qf < 2; ++qf)
            #pragma unroll
            for (int kc0 = 0; kc0 < 2; ++kc0)
                bp[qf][kc0] = *(const f16x8*)&Plds[wv][qf * 16 + ln][kc0 * 32 + g * 8];
        #pragma unroll
        for (int m = 0; m < 4; ++m)
            #pragma unroll
            for (int kc0 = 0; kc0 < 2; ++kc0)
                #pragma unroll
                for (int qf = 0; qf < 2; ++qf)
                    O[m][qf] = __builtin_amdgcn_mfma_f32_16x16x32_f16(av[m][kc0], bp[qf][kc0], O[m][qf], 0, 0, 0);

        #pragma unroll
        for (int m = 0; m < 4; ++m)
            #pragma unroll
            for (int k0 = 0; k0 < 2; ++k0)
                akc[m][k0] = akn[m][k0];
    }

    // ---- merge the 4 k-split partials ----
    __syncthreads();
    if (g == 0) {
        #pragma unroll
        for (int qf = 0; qf < 2; ++qf) {
            mlbuf[wv][qf][ln][0] = mrun[qf];
            mlbuf[wv][qf][ln][1] = lrun[qf];
        }
    }
    __syncthreads();

    float Lfin[2];
    #pragma unroll
    for (int qf = 0; qf < 2; ++qf) {
        float m0 = mlbuf[0][qf][ln][0], m1 = mlbuf[1][qf][ln][0];
        float m2 = mlbuf[2][qf][ln][0], m3 = mlbuf[3][qf][ln][0];
        const float mstar = fmaxf(fmaxf(m0, m1), fmaxf(m2, m3));
        float L = mlbuf[0][qf][ln][1] * exp2f(m0 - mstar)
                + mlbuf[1][qf][ln][1] * exp2f(m1 - mstar)
                + mlbuf[2][qf][ln][1] * exp2f(m2 - mstar)
                + mlbuf[3][qf][ln][1] * exp2f(m3 - mstar);
        Lfin[qf] = L;
        const float sc = exp2f(mrun[qf] - mstar);
        #pragma unroll
        for (int m = 0; m < 4; ++m) O[m][qf] *= sc;
    }

    if (wv >= 2) {
        #pragma unroll
        for (int qf = 0; qf < 2; ++qf)
            #pragma unroll
            for (int m = 0; m < 4; ++m)
                *(f32x4*)&Obuf[wv - 2][qf * 16 + ln][m * 16 + g * 4] = O[m][qf];
    }
    __syncthreads();
    if (wv < 2) {
        #pragma unroll
        for (int qf = 0; qf < 2; ++qf)
            #pragma unroll
            for (int m = 0; m < 4; ++m)
                O[m][qf] += *(const f32x4*)&Obuf[wv][qf * 16 + ln][m * 16 + g * 4];
    }
    __syncthreads();
    if (wv == 1) {
        #pragma unroll
        for (int qf = 0; qf < 2; ++qf)
            #pragma unroll
            for (int m = 0; m < 4; ++m)
                *(f32x4*)&Obuf[0][qf * 16 + ln][m * 16 + g * 4] = O[m][qf];
    }
    __syncthreads();
    if (wv == 0) {
        const int s_ = combo >> 3, b_ = (combo >> 2) & 1, h_ = combo & 3;
        #pragma unroll
        for (int qf = 0; qf < 2; ++qf) {
            const float inv = 1.f / Lfin[qf];
            const int tok = q0 + qf * 16 + ln;
            #pragma unroll
            for (int m = 0; m < 4; ++m) {
                f32x4 ov = O[m][qf];
                ov += *(const f32x4*)&Obuf[0][qf * 16 + ln][m * 16 + g * 4];
                ov *= inv;
                uint2 u;
                u.x = pk2(ov[0], ov[1]);
                u.y = pk2(ov[2], ov[3]);
                *(uint2*)&oc16[((size_t)(b_ * TT + tok)) * 1024 + s_ * 256 + h_ * 64 + m * 16 + g * 4] = u;
            }
        }
    }
}

// ---------------------------------------------------------------------------
extern "C" void kernel_launch(void* const* d_in, const int* in_sizes, int n_in,
                              void* d_out, int out_size, void* d_ws, size_t ws_size,
                              hipStream_t stream)
{
    const float* x    = (const float*)d_in[0];
    const float* wci  = (const float*)d_in[1];
    const float* b1g  = (const float*)d_in[2];
    const float* b1b  = (const float*)d_in[3];
    const float* b1m  = (const float*)d_in[4];
    const float* b1v  = (const float*)d_in[5];
    const float* dww  = (const float*)d_in[6];
    const float* pww  = (const float*)d_in[7];
    const float* b2g  = (const float*)d_in[8];
    const float* b2b  = (const float*)d_in[9];
    const float* b2m  = (const float*)d_in[10];
    const float* b2v  = (const float*)d_in[11];
    const float* Wq   = (const float*)d_in[12];
    const float* Wk   = (const float*)d_in[13];
    const float* Wv   = (const float*)d_in[14];
    const float* Wout = (const float*)d_in[15];

    char* wsb = (char*)d_ws;
    float*     ident = (float*)(wsb + WSB_IDENT);
    _Float16*  rt16  = (_Float16*)(wsb + WSB_RT16);
    float*     dwt   = (float*)(wsb + WSB_DWT);
    float*     ysch  = (float*)(wsb + WSB_YS);
    _Float16*  qh    = (_Float16*)(wsb + WSB_QH);
    _Float16*  khp   = (_Float16*)(wsb + WSB_KH);
    _Float16*  vtp   = (_Float16*)(wsb + WSB_VT);
    _Float16*  oc16  = (_Float16*)(wsb + WSB_OC16);
    _Float16*  w16   = (_Float16*)(wsb + WSB_W16);
    float*     outp  = (float*)d_out;

    // 0) weight conversion f32 -> f16 (wq, wk, wv, wout)
    wcvt<<<dim3(152), 256, 0, stream>>>(Wq, Wk, Wv, Wout, w16);

    // 1) conv_in (1x1) + BN1 -> identity f32 + rt16 scale0
    gemm64<0><<<dim3(BB * TT / 64, CIN / 64), 256, 0, stream>>>(
        x, wci, ident, (float*)rt16, b1g, b1b, b1m, b1v, CIN, 0);

    // 2) Res2Net chain: dw3x3 -> pw 1x1 + BN2 -> rt16[s] + ys_ch, scales 1..3
    for (int s = 1; s <= 3; ++s) {
        const float* yp = (s == 1) ? nullptr : (ysch + (size_t)(s - 2) * BB * C4 * TT);
        dw3x3<<<dim3(BB * C4 * TT / 256), 256, 0, stream>>>(ident, yp, dww, dwt, s);
        gemm64<1><<<dim3(BB * TT / 64, 1), 256, 0, stream>>>(
            dwt, pww, (float*)rt16, ysch, b2g, b2b, b2m, b2v, C4, s);
    }

    // 3) q/k/v projections, f16 MFMA -> qh (log2e-scaled), kh, vt (V^T)
    qkv_mfma<<<dim3(144, 8, 3), 256, 0, stream>>>(rt16, w16, qh, khp, vtp);

    // 4) f16 MFMA flash attention (k-split + XCD swizzle) -> oc16 f16
    attn_mfma<<<dim3(TT / 32 * 32), 256, 0, stream>>>(qh, khp, vtp, oc16);

    // 5) output projection, f16 MFMA -> d_out f32
    out_mfma<<<dim3(72, 8), 256, 0, stream>>>(oc16, w16 + 49152, outp);
}

// Round 12
// 227.816 us; speedup vs baseline: 3.5022x; 1.2171x over previous
//
#include <hip/hip_runtime.h>
#include <math.h>

#define BB 2
#define TT 2304
#define CIN 256
#define C4 64
#define NHEADS 4
#define DHV 64
#define HHH 48
#define WWW 48
#define EPSV 1e-5f
#define LOG2E 1.4426950408889634f

using f16x8 = __attribute__((ext_vector_type(8))) _Float16;
using f32x4 = __attribute__((ext_vector_type(4))) float;

typedef const __attribute__((address_space(1))) unsigned int gu32;
typedef __attribute__((address_space(3))) unsigned int lu32;

// pack two f32 -> one u32 of two f16 (RTZ), type-safe via bit_cast
__device__ __forceinline__ unsigned pk2(float a, float b) {
    return __builtin_bit_cast(unsigned, __builtin_amdgcn_cvt_pkrtz(a, b));
}

// workspace layout (byte offsets)
#define WSB_IDENT 0u          // [BB][CIN][TT] f32      4718592
#define WSB_RT16  4718592u    // [4][BB][TT][64] f16    2359296
#define WSB_DWT   7077888u    // [C4][BB*TT] f32        1179648
#define WSB_YS    8257536u    // [3][BB][C4][TT] f32    3538944
#define WSB_QH    11796480u   // [32][TT][64] f16       9437184  (log2e-scaled)
#define WSB_KH    21233664u   // [32][TT][64] f16       9437184
#define WSB_VT    30670848u   // [32][64][TT] f16       9437184  (V transposed)
#define WSB_OC16  40108032u   // [BB][TT][1024] f16     9437184
#define WSB_W16   49545216u   // wq,wk,wv (3x16384) + wout (262144) f16

// ---------------------------------------------------------------------------
// Weight conversion f32 -> f16: wq,wk,wv (16384 each), wout (262144).
// ---------------------------------------------------------------------------
__global__ __launch_bounds__(256) void wcvt(
    const float* __restrict__ s0, const float* __restrict__ s1,
    const float* __restrict__ s2, const float* __restrict__ s3,
    _Float16* __restrict__ w16)
{
    const int i = blockIdx.x * 256 + threadIdx.x;
    const float* s; _Float16* d; int off;
    if (i < 2048)      { s = s0; d = w16;          off = i; }
    else if (i < 4096) { s = s1; d = w16 + 16384;  off = i - 2048; }
    else if (i < 6144) { s = s2; d = w16 + 32768;  off = i - 4096; }
    else               { s = s3; d = w16 + 49152;  off = i - 6144; }
    float4 a = ((const float4*)s)[off * 2];
    float4 b = ((const float4*)s)[off * 2 + 1];
    uint4 u;
    u.x = pk2(a.x, a.y); u.y = pk2(a.z, a.w);
    u.z = pk2(b.x, b.y); u.w = pk2(b.z, b.w);
    ((uint4*)d)[off] = u;
}

// ---------------------------------------------------------------------------
// fp32 64x64-tile GEMM (conv_in and pointwise).
// MODE 0: conv_in + BN1 -> identity (ch-major f32) + rt16 scale0 (f16)
// MODE 1: pointwise + BN2 -> rt16[scale] (f16) + ys_ch[scale-1] (f32)
// ---------------------------------------------------------------------------
template<int MODE>
__global__ __launch_bounds__(256) void gemm64(
    const float* __restrict__ A, const float* __restrict__ W,
    float* __restrict__ out, float* __restrict__ out2,
    const float* __restrict__ bg, const float* __restrict__ bb,
    const float* __restrict__ bm, const float* __restrict__ bv,
    int Kdim, int scale_s)
{
    __shared__ __align__(16) float As[16][68];
    __shared__ __align__(16) float Ws[16][68];
    const int tid = threadIdx.x;
    const int m0 = blockIdx.x * 64;
    const int n0 = blockIdx.y * 64;
    const int tm = tid & 15, tn = tid >> 4;
    float acc[4][4] = {};
    for (int k0 = 0; k0 < Kdim; k0 += 16) {
        __syncthreads();
        if (MODE == 1) {
            const int kk = tid >> 4, mc = tid & 15;
            float4 a4 = *(const float4*)&A[(size_t)(k0 + kk) * (BB * TT) + m0 + mc * 4];
            *(float4*)&As[kk][mc * 4] = a4;
        } else {
            const int lr = tid >> 2, lc = tid & 3;
            float4 a4 = *(const float4*)&A[(size_t)(m0 + lr) * Kdim + k0 + lc * 4];
            As[lc * 4 + 0][lr] = a4.x; As[lc * 4 + 1][lr] = a4.y;
            As[lc * 4 + 2][lr] = a4.z; As[lc * 4 + 3][lr] = a4.w;
        }
        {
            const int lr = tid >> 2, lc = tid & 3;
            float4 w4 = *(const float4*)&W[(size_t)(n0 + lr) * Kdim + k0 + lc * 4];
            Ws[lc * 4 + 0][lr] = w4.x; Ws[lc * 4 + 1][lr] = w4.y;
            Ws[lc * 4 + 2][lr] = w4.z; Ws[lc * 4 + 3][lr] = w4.w;
        }
        __syncthreads();
        #pragma unroll
        for (int kk = 0; kk < 16; ++kk) {
            float4 af = *(const float4*)&As[kk][tm * 4];
            float4 wf = *(const float4*)&Ws[kk][tn * 4];
            float av[4] = {af.x, af.y, af.z, af.w};
            float wv[4] = {wf.x, wf.y, wf.z, wf.w};
            #pragma unroll
            for (int i = 0; i < 4; ++i)
                #pragma unroll
                for (int j = 0; j < 4; ++j)
                    acc[i][j] = fmaf(av[i], wv[j], acc[i][j]);
        }
    }

    if (MODE == 0) {
        _Float16* rt16 = (_Float16*)out2;
        #pragma unroll
        for (int j = 0; j < 4; ++j) {
            const int o = n0 + tn * 4 + j;
            const float inv = bg[o] * rsqrtf(bv[o] + EPSV);
            const float bet = bb[o] - bm[o] * inv;
            #pragma unroll
            for (int i = 0; i < 4; ++i) {
                const int m = m0 + tm * 4 + i;
                const int b = m / TT, t = m % TT;
                const float val = acc[i][j] * inv + bet;
                out[((size_t)(b * CIN + o)) * TT + t] = val;
                if (o < C4) rt16[((size_t)(b * TT + t)) * C4 + o] = (_Float16)val;
            }
        }
    } else {
        _Float16* rt16 = (_Float16*)out;
        #pragma unroll
        for (int j = 0; j < 4; ++j) {
            const int o = n0 + tn * 4 + j;
            const float inv = bg[o] * rsqrtf(bv[o] + EPSV);
            const float bet = bb[o] - bm[o] * inv;
            #pragma unroll
            for (int i = 0; i < 4; ++i) {
                const int m = m0 + tm * 4 + i;
                const int b = m / TT, t = m % TT;
                const float val = acc[i][j] * inv + bet;
                rt16[(((size_t)scale_s * BB + b) * TT + t) * C4 + o] = (_Float16)val;
                out2[(((size_t)(scale_s - 1) * BB + b) * C4 + o) * TT + t] = val;
            }
        }
    }
}

// ---------------------------------------------------------------------------
// Depthwise 3x3 SAME, output col-major [C4][BB*TT].
// ---------------------------------------------------------------------------
__global__ __launch_bounds__(256) void dw3x3(
    const float* __restrict__ ident, const float* __restrict__ ysprev,
    const float* __restrict__ dww, float* __restrict__ dwt, int s)
{
    const int g = blockIdx.x * 256 + threadIdx.x;
    const int t = g % TT;
    const int c = (g / TT) & (C4 - 1);
    const int b = g / (TT * C4);
    const int h = t / WWW, w = t % WWW;
    const float* p1 = ident + ((size_t)(b * CIN + s * C4 + c)) * TT;
    const float* p2 = ysprev ? (ysprev + ((size_t)(b * C4 + c)) * TT) : nullptr;
    float acc = 0.f;
    #pragma unroll
    for (int kh = 0; kh < 3; ++kh) {
        const int hh2 = h + kh - 1;
        if (hh2 < 0 || hh2 >= HHH) continue;
        #pragma unroll
        for (int kw = 0; kw < 3; ++kw) {
            const int ww2 = w + kw - 1;
            if (ww2 < 0 || ww2 >= WWW) continue;
            const int t2 = hh2 * WWW + ww2;
            float v = p1[t2];
            if (p2) v += p2[t2];
            acc = fmaf(v, dww[c * 9 + kh * 3 + kw], acc);
        }
    }
    dwt[(size_t)c * (BB * TT) + b * TT + t] = acc;
}

// ---------------------------------------------------------------------------
// q/k/v projection, f16 MFMA (unchanged from round 11).
// ---------------------------------------------------------------------------
__global__ __launch_bounds__(256) void qkv_mfma(
    const _Float16* __restrict__ rt16, const _Float16* __restrict__ w16,
    _Float16* __restrict__ qh, _Float16* __restrict__ kh, _Float16* __restrict__ vt)
{
    const int tid = threadIdx.x;
    const int wv = tid >> 6;
    const int lane = tid & 63;
    const int g = lane >> 4, ln = lane & 15;
    const int z = blockIdx.z;
    const _Float16* W = w16 + z * 16384;
    const int m0 = blockIdx.x * 128 + wv * 32;
    const int o0 = blockIdx.y * 32;
    const int s = m0 / (BB * TT);
    const int rem = m0 - s * (BB * TT);
    const int b = rem / TT;
    const int t0 = rem - b * TT;
    const int h = o0 >> 6;
    const int dbase = (o0 & 63);
    const int combo = (s * BB + b) * NHEADS + h;

    if (z < 2) {
        f16x8 a[2][2], bf[2][2];
        #pragma unroll
        for (int mi = 0; mi < 2; ++mi)
            #pragma unroll
            for (int ks = 0; ks < 2; ++ks)
                a[mi][ks] = *(const f16x8*)(rt16 + ((size_t)(m0 + mi * 16 + ln)) * 64 + ks * 32 + g * 8);
        #pragma unroll
        for (int oi = 0; oi < 2; ++oi)
            #pragma unroll
            for (int ks = 0; ks < 2; ++ks)
                bf[oi][ks] = *(const f16x8*)(W + ((size_t)(o0 + oi * 16 + ln)) * 64 + ks * 32 + g * 8);
        f32x4 acc[2][2] = {};
        #pragma unroll
        for (int ks = 0; ks < 2; ++ks)
            #pragma unroll
            for (int mi = 0; mi < 2; ++mi)
                #pragma unroll
                for (int oi = 0; oi < 2; ++oi)
                    acc[mi][oi] = __builtin_amdgcn_mfma_f32_16x16x32_f16(a[mi][ks], bf[oi][ks], acc[mi][oi], 0, 0, 0);
        _Float16* dst = (z == 0) ? qh : kh;
        const float sc = (z == 0) ? LOG2E : 1.f;
        #pragma unroll
        for (int mi = 0; mi < 2; ++mi)
            #pragma unroll
            for (int oi = 0; oi < 2; ++oi) {
                const int d = dbase + oi * 16 + ln;
                #pragma unroll
                for (int r = 0; r < 4; ++r) {
                    const int t = t0 + mi * 16 + g * 4 + r;
                    dst[((size_t)combo * TT + t) * DHV + d] = (_Float16)(acc[mi][oi][r] * sc);
                }
            }
    } else {
        f16x8 a[2][2], bf[2][2];
        #pragma unroll
        for (int oi = 0; oi < 2; ++oi)
            #pragma unroll
            for (int ks = 0; ks < 2; ++ks)
                a[oi][ks] = *(const f16x8*)(W + ((size_t)(o0 + oi * 16 + ln)) * 64 + ks * 32 + g * 8);
        #pragma unroll
        for (int ti = 0; ti < 2; ++ti)
            #pragma unroll
            for (int ks = 0; ks < 2; ++ks)
                bf[ti][ks] = *(const f16x8*)(rt16 + ((size_t)(m0 + ti * 16 + ln)) * 64 + ks * 32 + g * 8);
        f32x4 acc[2][2] = {};
        #pragma unroll
        for (int ks = 0; ks < 2; ++ks)
            #pragma unroll
            for (int oi = 0; oi < 2; ++oi)
                #pragma unroll
                for (int ti = 0; ti < 2; ++ti)
                    acc[oi][ti] = __builtin_amdgcn_mfma_f32_16x16x32_f16(a[oi][ks], bf[ti][ks], acc[oi][ti], 0, 0, 0);
        #pragma unroll
        for (int oi = 0; oi < 2; ++oi)
            #pragma unroll
            for (int ti = 0; ti < 2; ++ti) {
                const int t = t0 + ti * 16 + ln;
                #pragma unroll
                for (int r = 0; r < 4; ++r) {
                    const int d = dbase + oi * 16 + g * 4 + r;
                    vt[((size_t)combo * DHV + d) * TT + t] = (_Float16)acc[oi][ti][r];
                }
            }
    }
}

// ---------------------------------------------------------------------------
// Output projection, f16 MFMA (unchanged from round 11).
// ---------------------------------------------------------------------------
__global__ __launch_bounds__(256) void out_mfma(
    const _Float16* __restrict__ oc16, const _Float16* __restrict__ wout16,
    float* __restrict__ out)
{
    const int tid = threadIdx.x;
    const int wv = tid >> 6;
    const int lane = tid & 63;
    const int g = lane >> 4, ln = lane & 15;
    const int m0 = blockIdx.x * 64 + wv * 16;
    const int o0 = blockIdx.y * 32;
    f32x4 acc[2] = {};
    for (int k0 = 0; k0 < 1024; k0 += 32) {
        f16x8 a = *(const f16x8*)(oc16 + ((size_t)(m0 + ln)) * 1024 + k0 + g * 8);
        #pragma unroll
        for (int oi = 0; oi < 2; ++oi) {
            f16x8 bf = *(const f16x8*)(wout16 + ((size_t)(o0 + oi * 16 + ln)) * 1024 + k0 + g * 8);
            acc[oi] = __builtin_amdgcn_mfma_f32_16x16x32_f16(a, bf, acc[oi], 0, 0, 0);
        }
    }
    #pragma unroll
    for (int oi = 0; oi < 2; ++oi)
        #pragma unroll
        for (int r = 0; r < 4; ++r)
            out[((size_t)(m0 + g * 4 + r)) * CIN + o0 + oi * 16 + ln] = acc[oi][r];
}

// ---------------------------------------------------------------------------
// f16 MFMA flash attention, LDS-staged K/V shared by 4 waves (T3/T14 style).
// Block = 4 waves x 16 q-rows = 64 q-rows of one combo; full 2304 keys each;
// no k-split, no merge. Grid 36x32 = 1152 blocks (XCD-affine: bid&7 -> combo
// group), 4608 waves.
// Per iter (KVBLK=64): stage K(i+1) into Kls[cur^1] and V(i) into Vls via
// global_load_lds (fire-and-forget: compiler CANNOT sink it - fixes the
// r8-r11 prefetch-discard failure). QK^T + softmax hide the stage latency;
// __syncthreads() (drains vmcnt) -> PV reads Vls -> barrier.
// LDS tiles XOR-swizzled (chunk ^= row&7): applied on the SOURCE global
// address at staging (linear LDS dest) and on ds_read_b128 (m173/m201).
// S^T = mfma(A=K,B=Q^T): softmax rows lane-local (16 vals + 2 shfl_xor).
// P roundtrips wave-private LDS; O^T = mfma(A=V^T from LDS, B=P).
// ---------------------------------------------------------------------------
__global__ __launch_bounds__(256, 4) void attn_mfma(
    const _Float16* __restrict__ qh, const _Float16* __restrict__ kh,
    const _Float16* __restrict__ vt, _Float16* __restrict__ oc16)
{
    __shared__ __align__(16) _Float16 Kls[2][4096];   // [64 rows][64 f16] swizzled
    __shared__ __align__(16) _Float16 Vls[4096];      // [64 d][64 k] swizzled
    __shared__ __align__(16) _Float16 Plds[4][16][88];

    const int tid = threadIdx.x;
    const int wv = tid >> 6;
    const int lane = tid & 63;
    const int g = lane >> 4, ln = lane & 15;
    // XCD-affinity: 1152 = 8 x 144; xcd owns combos 4*xcd..4*xcd+3
    const int bid = blockIdx.x;
    const int xcd = bid & 7, slot = bid >> 3;          // slot 0..143
    const int combo = (xcd << 2) | (slot / 36);
    const int q0 = (slot % 36) * 64 + wv * 16;         // wave's 16 q-rows
    const _Float16* Q = qh + (size_t)combo * TT * DHV;
    const _Float16* K = kh + (size_t)combo * TT * DHV;
    const _Float16* V = vt + (size_t)combo * DHV * TT;

    // staging geometry: wave stages 2x1KB per tile; per-lane source swizzle
    const int srow = wv * 16 + (lane >> 3);            // + j*8 per call
    const int scol = (((lane & 7) ^ ((lane >> 3) & 7))) * 8;  // f16 elems
    const int ldsoff = wv * 1024 + (lane & 7) * 0;     // base f16 idx = (wv*2+j)*512
    (void)ldsoff;
    const int sw = (ln & 7) << 3;                      // ds_read elem-index XOR

    // Q B-frags, held for the whole kernel
    f16x8 bq[2];
    #pragma unroll
    for (int k0 = 0; k0 < 2; ++k0)
        bq[k0] = *(const f16x8*)(Q + ((size_t)(q0 + ln)) * DHV + k0 * 32 + g * 8);

    f32x4 O[4] = {};
    float mrun = -1e30f, lrun = 0.f;

    // prologue: stage K(0) into Kls[0]
    #pragma unroll
    for (int j = 0; j < 2; ++j)
        __builtin_amdgcn_global_load_lds(
            (gu32*)(K + (size_t)(srow + j * 8) * DHV + scol),
            (lu32*)&Kls[0][(wv * 2 + j) * 512], 16, 0, 0);
    __syncthreads();

    int cur = 0;
    for (int it = 0; it < TT / 64; ++it) {
        const int kb = it * 64;
        const int kn = (it + 1 < TT / 64) ? kb + 64 : 0;

        // ---- stage K(next) -> Kls[cur^1], V(cur) -> Vls (cannot sink) ----
        #pragma unroll
        for (int j = 0; j < 2; ++j)
            __builtin_amdgcn_global_load_lds(
                (gu32*)(K + (size_t)(kn + srow + j * 8) * DHV + scol),
                (lu32*)&Kls[cur ^ 1][(wv * 2 + j) * 512], 16, 0, 0);
        #pragma unroll
        for (int j = 0; j < 2; ++j)
            __builtin_amdgcn_global_load_lds(
                (gu32*)(V + (size_t)(srow + j * 8) * TT + kb + scol),
                (lu32*)&Vls[(wv * 2 + j) * 512], 16, 0, 0);

        // ---- QK^T (swapped) from Kls[cur] (swizzled reads) ----
        f32x4 S[4] = {};
        __builtin_amdgcn_s_setprio(1);
        #pragma unroll
        for (int m = 0; m < 4; ++m) {
            f16x8 ak0 = *(const f16x8*)&Kls[cur][(((m * 16 + ln) * 64) + 0 * 32 + g * 8) ^ sw];
            f16x8 ak1 = *(const f16x8*)&Kls[cur][(((m * 16 + ln) * 64) + 1 * 32 + g * 8) ^ sw];
            S[m] = __builtin_amdgcn_mfma_f32_16x16x32_f16(ak0, bq[0], S[m], 0, 0, 0);
            S[m] = __builtin_amdgcn_mfma_f32_16x16x32_f16(ak1, bq[1], S[m], 0, 0, 0);
        }
        __builtin_amdgcn_s_setprio(0);

        // ---- online softmax (rows lane-local; exp2 domain; tree) ----
        {
            float a0 = fmaxf(fmaxf(S[0][0], S[0][1]), fmaxf(S[0][2], S[0][3]));
            float a1 = fmaxf(fmaxf(S[1][0], S[1][1]), fmaxf(S[1][2], S[1][3]));
            float a2 = fmaxf(fmaxf(S[2][0], S[2][1]), fmaxf(S[2][2], S[2][3]));
            float a3 = fmaxf(fmaxf(S[3][0], S[3][1]), fmaxf(S[3][2], S[3][3]));
            float mx = fmaxf(fmaxf(a0, a1), fmaxf(a2, a3));
            mx = fmaxf(mx, __shfl_xor(mx, 16));
            mx = fmaxf(mx, __shfl_xor(mx, 32));
            const float mnew = fmaxf(mrun, mx);
            const float corr = exp2f(mrun - mnew);
            float psm[4];
            #pragma unroll
            for (int m = 0; m < 4; ++m) {
                #pragma unroll
                for (int r = 0; r < 4; ++r)
                    S[m][r] = exp2f(S[m][r] - mnew);
                psm[m] = (S[m][0] + S[m][1]) + (S[m][2] + S[m][3]);
            }
            float ps = (psm[0] + psm[1]) + (psm[2] + psm[3]);
            ps += __shfl_xor(ps, 16);
            ps += __shfl_xor(ps, 32);
            lrun = lrun * corr + ps;
            mrun = mnew;
            #pragma unroll
            for (int m = 0; m < 4; ++m) O[m] *= corr;
            #pragma unroll
            for (int m = 0; m < 4; ++m) {
                uint2 u;
                u.x = pk2(S[m][0], S[m][1]);
                u.y = pk2(S[m][2], S[m][3]);
                *(uint2*)&Plds[wv][ln][m * 16 + g * 4] = u;
            }
        }

        // all stages landed (vmcnt drained by barrier); Vls valid block-wide
        __syncthreads();

        // ---- PV (swapped): O^T += V^T_blk . P, V from Vls (swizzled) ----
        f16x8 bp[2];
        #pragma unroll
        for (int kc0 = 0; kc0 < 2; ++kc0)
            bp[kc0] = *(const f16x8*)&Plds[wv][ln][kc0 * 32 + g * 8];
        __builtin_amdgcn_s_setprio(1);
        #pragma unroll
        for (int m = 0; m < 4; ++m) {
            f16x8 av0 = *(const f16x8*)&Vls[(((m * 16 + ln) * 64) + 0 * 32 + g * 8) ^ sw];
            f16x8 av1 = *(const f16x8*)&Vls[(((m * 16 + ln) * 64) + 1 * 32 + g * 8) ^ sw];
            O[m] = __builtin_amdgcn_mfma_f32_16x16x32_f16(av0, bp[0], O[m], 0, 0, 0);
            O[m] = __builtin_amdgcn_mfma_f32_16x16x32_f16(av1, bp[1], O[m], 0, 0, 0);
        }
        __builtin_amdgcn_s_setprio(0);

        // all reads of Vls / Kls[cur] done before next iter's stages
        __syncthreads();
        cur ^= 1;
    }

    // ---- epilogue: wave-private 16 q-rows, direct write ----
    const int s_ = combo >> 3, b_ = (combo >> 2) & 1, h_ = combo & 3;
    const float inv = 1.f / lrun;
    const int tok = q0 + ln;
    #pragma unroll
    for (int m = 0; m < 4; ++m) {
        uint2 u;
        u.x = pk2(O[m][0] * inv, O[m][1] * inv);
        u.y = pk2(O[m][2] * inv, O[m][3] * inv);
        *(uint2*)&oc16[((size_t)(b_ * TT + tok)) * 1024 + s_ * 256 + h_ * 64 + m * 16 + g * 4] = u;
    }
}

// ---------------------------------------------------------------------------
extern "C" void kernel_launch(void* const* d_in, const int* in_sizes, int n_in,
                              void* d_out, int out_size, void* d_ws, size_t ws_size,
                              hipStream_t stream)
{
    const float* x    = (const float*)d_in[0];
    const float* wci  = (const float*)d_in[1];
    const float* b1g  = (const float*)d_in[2];
    const float* b1b  = (const float*)d_in[3];
    const float* b1m  = (const float*)d_in[4];
    const float* b1v  = (const float*)d_in[5];
    const float* dww  = (const float*)d_in[6];
    const float* pww  = (const float*)d_in[7];
    const float* b2g  = (const float*)d_in[8];
    const float* b2b  = (const float*)d_in[9];
    const float* b2m  = (const float*)d_in[10];
    const float* b2v  = (const float*)d_in[11];
    const float* Wq   = (const float*)d_in[12];
    const float* Wk   = (const float*)d_in[13];
    const float* Wv   = (const float*)d_in[14];
    const float* Wout = (const float*)d_in[15];

    char* wsb = (char*)d_ws;
    float*     ident = (float*)(wsb + WSB_IDENT);
    _Float16*  rt16  = (_Float16*)(wsb + WSB_RT16);
    float*     dwt   = (float*)(wsb + WSB_DWT);
    float*     ysch  = (float*)(wsb + WSB_YS);
    _Float16*  qh    = (_Float16*)(wsb + WSB_QH);
    _Float16*  khp   = (_Float16*)(wsb + WSB_KH);
    _Float16*  vtp   = (_Float16*)(wsb + WSB_VT);
    _Float16*  oc16  = (_Float16*)(wsb + WSB_OC16);
    _Float16*  w16   = (_Float16*)(wsb + WSB_W16);
    float*     outp  = (float*)d_out;

    // 0) weight conversion f32 -> f16 (wq, wk, wv, wout)
    wcvt<<<dim3(152), 256, 0, stream>>>(Wq, Wk, Wv, Wout, w16);

    // 1) conv_in (1x1) + BN1 -> identity f32 + rt16 scale0
    gemm64<0><<<dim3(BB * TT / 64, CIN / 64), 256, 0, stream>>>(
        x, wci, ident, (float*)rt16, b1g, b1b, b1m, b1v, CIN, 0);

    // 2) Res2Net chain: dw3x3 -> pw 1x1 + BN2 -> rt16[s] + ys_ch, scales 1..3
    for (int s = 1; s <= 3; ++s) {
        const float* yp = (s == 1) ? nullptr : (ysch + (size_t)(s - 2) * BB * C4 * TT);
        dw3x3<<<dim3(BB * C4 * TT / 256), 256, 0, stream>>>(ident, yp, dww, dwt, s);
        gemm64<1><<<dim3(BB * TT / 64, 1), 256, 0, stream>>>(
            dwt, pww, (float*)rt16, ysch, b2g, b2b, b2m, b2v, C4, s);
    }

    // 3) q/k/v projections, f16 MFMA -> qh (log2e-scaled), kh, vt (V^T)
    qkv_mfma<<<dim3(144, 8, 3), 256, 0, stream>>>(rt16, w16, qh, khp, vtp);

    // 4) f16 MFMA flash attention (LDS-staged shared K/V) -> oc16 f16
    attn_mfma<<<dim3(36 * 32), 256, 0, stream>>>(qh, khp, vtp, oc16);

    // 5) output projection, f16 MFMA -> d_out f32
    out_mfma<<<dim3(72, 8), 256, 0, stream>>>(oc16, w16 + 49152, outp);
}

// Round 14
// 216.020 us; speedup vs baseline: 3.6934x; 1.0546x over previous
//
#include <hip/hip_runtime.h>
#include <math.h>

#define BB 2
#define TT 2304
#define CIN 256
#define C4 64
#define NHEADS 4
#define DHV 64
#define HHH 48
#define WWW 48
#define EPSV 1e-5f
#define LOG2E 1.4426950408889634f

using f16x8 = __attribute__((ext_vector_type(8))) _Float16;
using f32x4 = __attribute__((ext_vector_type(4))) float;

typedef const __attribute__((address_space(1))) unsigned int gu32;
typedef __attribute__((address_space(3))) unsigned int lu32;

// pack two f32 -> one u32 of two f16 (RTZ), type-safe via bit_cast
__device__ __forceinline__ unsigned pk2(float a, float b) {
    return __builtin_bit_cast(unsigned, __builtin_amdgcn_cvt_pkrtz(a, b));
}

__device__ __forceinline__ f32x4 MFMA(f16x8 a, f16x8 b, f32x4 c) {
    return __builtin_amdgcn_mfma_f32_16x16x32_f16(a, b, c, 0, 0, 0);
}

// workspace layout (byte offsets)
#define WSB_IDENT 0u          // [BB][CIN][TT] f32      4718592
#define WSB_RT16  4718592u    // [4][BB][TT][64] f16    2359296
#define WSB_DWT   7077888u    // [C4][BB*TT] f32        1179648
#define WSB_YS    8257536u    // [3][BB][C4][TT] f32    3538944
#define WSB_QH    11796480u   // [32][TT][64] f16       9437184  (log2e-scaled)
#define WSB_KH    21233664u   // [32][TT][64] f16       9437184
#define WSB_VT    30670848u   // [32][64][TT] f16       9437184  (V transposed)
#define WSB_OC16  40108032u   // [BB][TT][1024] f16     9437184
#define WSB_W16   49545216u   // wq,wk,wv(3x16384) wout(262144) wci(65536) f16
#define WSB_X16   50298880u   // [BB*TT][256] f16       2359296

// ---------------------------------------------------------------------------
// f32 -> f16 conversion. Units of 8 f32: wq/wk/wv 2048 each, wout 32768,
// wci 8192, x 147456 -> total 194560 = 760 blocks x 256 exactly.
// (Round-13 bug: x was sized 294912 units -> OOB read -> abort. Fixed.)
// ---------------------------------------------------------------------------
__global__ __launch_bounds__(256) void wcvt(
    const float* __restrict__ wq, const float* __restrict__ wk,
    const float* __restrict__ wv, const float* __restrict__ wo,
    const float* __restrict__ wc, const float* __restrict__ xx,
    _Float16* __restrict__ w16, _Float16* __restrict__ x16)
{
    const int i = blockIdx.x * 256 + threadIdx.x;
    const float* s; _Float16* d; int off;
    if (i < 2048)       { s = wq; d = w16;           off = i; }
    else if (i < 4096)  { s = wk; d = w16 + 16384;   off = i - 2048; }
    else if (i < 6144)  { s = wv; d = w16 + 32768;   off = i - 4096; }
    else if (i < 38912) { s = wo; d = w16 + 49152;   off = i - 6144; }
    else if (i < 47104) { s = wc; d = w16 + 311296;  off = i - 38912; }
    else                { s = xx; d = x16;           off = i - 47104; }
    float4 a = ((const float4*)s)[off * 2];
    float4 b = ((const float4*)s)[off * 2 + 1];
    uint4 u;
    u.x = pk2(a.x, a.y); u.y = pk2(a.z, a.w);
    u.z = pk2(b.x, b.y); u.w = pk2(b.z, b.w);
    ((uint4*)d)[off] = u;
}

// ---------------------------------------------------------------------------
// conv_in (1x1, K=256) + BN1 as f16 MFMA -> identity f32 (ch-major) and
// rt16 scale0 (tok-major, blocks with o0==0 only).
// Block 128t x 64o, 4 waves (wave = 32t x 64o). D[row=g*4+r <- t][col=ln <- o].
// ---------------------------------------------------------------------------
__global__ __launch_bounds__(256) void cin_mfma(
    const _Float16* __restrict__ x16, const _Float16* __restrict__ wci16,
    const float* __restrict__ bg, const float* __restrict__ bb,
    const float* __restrict__ bm, const float* __restrict__ bv,
    float* __restrict__ ident, _Float16* __restrict__ rt16)
{
    const int tid = threadIdx.x;
    const int wv = tid >> 6;
    const int lane = tid & 63;
    const int g = lane >> 4, ln = lane & 15;
    const int m0 = blockIdx.x * 128 + wv * 32;
    const int o0 = blockIdx.y * 64;
    const int b = m0 / TT;
    const int t0 = m0 - b * TT;

    f32x4 acc[2][4] = {};
    for (int ks = 0; ks < 8; ++ks) {
        f16x8 a0 = *(const f16x8*)(x16 + ((size_t)(m0 + ln)) * 256 + ks * 32 + g * 8);
        f16x8 a1 = *(const f16x8*)(x16 + ((size_t)(m0 + 16 + ln)) * 256 + ks * 32 + g * 8);
        #pragma unroll
        for (int oi = 0; oi < 4; ++oi) {
            f16x8 bf = *(const f16x8*)(wci16 + ((size_t)(o0 + oi * 16 + ln)) * 256 + ks * 32 + g * 8);
            acc[0][oi] = MFMA(a0, bf, acc[0][oi]);
            acc[1][oi] = MFMA(a1, bf, acc[1][oi]);
        }
    }
    #pragma unroll
    for (int oi = 0; oi < 4; ++oi) {
        const int o = o0 + oi * 16 + ln;
        const float inv = bg[o] * rsqrtf(bv[o] + EPSV);
        const float bet = bb[o] - bm[o] * inv;
        #pragma unroll
        for (int mi = 0; mi < 2; ++mi)
            #pragma unroll
            for (int r = 0; r < 4; ++r) {
                const int t = t0 + mi * 16 + g * 4 + r;
                const float val = acc[mi][oi][r] * inv + bet;
                ident[((size_t)(b * CIN + o)) * TT + t] = val;
                if (o0 == 0) rt16[((size_t)(b * TT + t)) * C4 + o] = (_Float16)val;
            }
    }
}

// ---------------------------------------------------------------------------
// Pointwise 1x1 (K=64) + BN2, fp32: A [K][M] col-major (dwt), W [N][K].
// -> rt16[scale] (f16 tok-major) + ys_ch[scale-1] (f32 ch-major).
// ---------------------------------------------------------------------------
__global__ __launch_bounds__(256) void pw_gemm(
    const float* __restrict__ A, const float* __restrict__ W,
    float* __restrict__ out, float* __restrict__ out2,
    const float* __restrict__ bg, const float* __restrict__ bb,
    const float* __restrict__ bm, const float* __restrict__ bv,
    int scale_s)
{
    __shared__ __align__(16) float As[16][68];
    __shared__ __align__(16) float Ws[16][68];
    const int tid = threadIdx.x;
    const int m0 = blockIdx.x * 64;
    const int tm = tid & 15, tn = tid >> 4;
    float acc[4][4] = {};
    for (int k0 = 0; k0 < C4; k0 += 16) {
        __syncthreads();
        {
            const int kk = tid >> 4, mc = tid & 15;
            float4 a4 = *(const float4*)&A[(size_t)(k0 + kk) * (BB * TT) + m0 + mc * 4];
            *(float4*)&As[kk][mc * 4] = a4;
        }
        {
            const int lr = tid >> 2, lc = tid & 3;
            float4 w4 = *(const float4*)&W[(size_t)lr * C4 + k0 + lc * 4];
            Ws[lc * 4 + 0][lr] = w4.x; Ws[lc * 4 + 1][lr] = w4.y;
            Ws[lc * 4 + 2][lr] = w4.z; Ws[lc * 4 + 3][lr] = w4.w;
        }
        __syncthreads();
        #pragma unroll
        for (int kk = 0; kk < 16; ++kk) {
            float4 af = *(const float4*)&As[kk][tm * 4];
            float4 wf = *(const float4*)&Ws[kk][tn * 4];
            float av[4] = {af.x, af.y, af.z, af.w};
            float wv[4] = {wf.x, wf.y, wf.z, wf.w};
            #pragma unroll
            for (int i = 0; i < 4; ++i)
                #pragma unroll
                for (int j = 0; j < 4; ++j)
                    acc[i][j] = fmaf(av[i], wv[j], acc[i][j]);
        }
    }
    _Float16* rt16 = (_Float16*)out;
    #pragma unroll
    for (int j = 0; j < 4; ++j) {
        const int o = tn * 4 + j;
        const float inv = bg[o] * rsqrtf(bv[o] + EPSV);
        const float bet = bb[o] - bm[o] * inv;
        #pragma unroll
        for (int i = 0; i < 4; ++i) {
            const int m = m0 + tm * 4 + i;
            const int b = m / TT, t = m % TT;
            const float val = acc[i][j] * inv + bet;
            rt16[(((size_t)scale_s * BB + b) * TT + t) * C4 + o] = (_Float16)val;
            out2[(((size_t)(scale_s - 1) * BB + b) * C4 + o) * TT + t] = val;
        }
    }
}

// ---------------------------------------------------------------------------
// Depthwise 3x3 SAME, output col-major [C4][BB*TT].
// ---------------------------------------------------------------------------
__global__ __launch_bounds__(256) void dw3x3(
    const float* __restrict__ ident, const float* __restrict__ ysprev,
    const float* __restrict__ dww, float* __restrict__ dwt, int s)
{
    const int g = blockIdx.x * 256 + threadIdx.x;
    const int t = g % TT;
    const int c = (g / TT) & (C4 - 1);
    const int b = g / (TT * C4);
    const int h = t / WWW, w = t % WWW;
    const float* p1 = ident + ((size_t)(b * CIN + s * C4 + c)) * TT;
    const float* p2 = ysprev ? (ysprev + ((size_t)(b * C4 + c)) * TT) : nullptr;
    float acc = 0.f;
    #pragma unroll
    for (int kh = 0; kh < 3; ++kh) {
        const int hh2 = h + kh - 1;
        if (hh2 < 0 || hh2 >= HHH) continue;
        #pragma unroll
        for (int kw = 0; kw < 3; ++kw) {
            const int ww2 = w + kw - 1;
            if (ww2 < 0 || ww2 >= WWW) continue;
            const int t2 = hh2 * WWW + ww2;
            float v = p1[t2];
            if (p2) v += p2[t2];
            acc = fmaf(v, dww[c * 9 + kh * 3 + kw], acc);
        }
    }
    dwt[(size_t)c * (BB * TT) + b * TT + t] = acc;
}

// ---------------------------------------------------------------------------
// q/k/v projection, f16 MFMA (unchanged).
// ---------------------------------------------------------------------------
__global__ __launch_bounds__(256) void qkv_mfma(
    const _Float16* __restrict__ rt16, const _Float16* __restrict__ w16,
    _Float16* __restrict__ qh, _Float16* __restrict__ kh, _Float16* __restrict__ vt)
{
    const int tid = threadIdx.x;
    const int wv = tid >> 6;
    const int lane = tid & 63;
    const int g = lane >> 4, ln = lane & 15;
    const int z = blockIdx.z;
    const _Float16* W = w16 + z * 16384;
    const int m0 = blockIdx.x * 128 + wv * 32;
    const int o0 = blockIdx.y * 32;
    const int s = m0 / (BB * TT);
    const int rem = m0 - s * (BB * TT);
    const int b = rem / TT;
    const int t0 = rem - b * TT;
    const int h = o0 >> 6;
    const int dbase = (o0 & 63);
    const int combo = (s * BB + b) * NHEADS + h;

    if (z < 2) {
        f16x8 a[2][2], bf[2][2];
        #pragma unroll
        for (int mi = 0; mi < 2; ++mi)
            #pragma unroll
            for (int ks = 0; ks < 2; ++ks)
                a[mi][ks] = *(const f16x8*)(rt16 + ((size_t)(m0 + mi * 16 + ln)) * 64 + ks * 32 + g * 8);
        #pragma unroll
        for (int oi = 0; oi < 2; ++oi)
            #pragma unroll
            for (int ks = 0; ks < 2; ++ks)
                bf[oi][ks] = *(const f16x8*)(W + ((size_t)(o0 + oi * 16 + ln)) * 64 + ks * 32 + g * 8);
        f32x4 acc[2][2] = {};
        #pragma unroll
        for (int ks = 0; ks < 2; ++ks)
            #pragma unroll
            for (int mi = 0; mi < 2; ++mi)
                #pragma unroll
                for (int oi = 0; oi < 2; ++oi)
                    acc[mi][oi] = MFMA(a[mi][ks], bf[oi][ks], acc[mi][oi]);
        _Float16* dst = (z == 0) ? qh : kh;
        const float sc = (z == 0) ? LOG2E : 1.f;
        #pragma unroll
        for (int mi = 0; mi < 2; ++mi)
            #pragma unroll
            for (int oi = 0; oi < 2; ++oi) {
                const int d = dbase + oi * 16 + ln;
                #pragma unroll
                for (int r = 0; r < 4; ++r) {
                    const int t = t0 + mi * 16 + g * 4 + r;
                    dst[((size_t)combo * TT + t) * DHV + d] = (_Float16)(acc[mi][oi][r] * sc);
                }
            }
    } else {
        f16x8 a[2][2], bf[2][2];
        #pragma unroll
        for (int oi = 0; oi < 2; ++oi)
            #pragma unroll
            for (int ks = 0; ks < 2; ++ks)
                a[oi][ks] = *(const f16x8*)(W + ((size_t)(o0 + oi * 16 + ln)) * 64 + ks * 32 + g * 8);
        #pragma unroll
        for (int ti = 0; ti < 2; ++ti)
            #pragma unroll
            for (int ks = 0; ks < 2; ++ks)
                bf[ti][ks] = *(const f16x8*)(rt16 + ((size_t)(m0 + ti * 16 + ln)) * 64 + ks * 32 + g * 8);
        f32x4 acc[2][2] = {};
        #pragma unroll
        for (int ks = 0; ks < 2; ++ks)
            #pragma unroll
            for (int oi = 0; oi < 2; ++oi)
                #pragma unroll
                for (int ti = 0; ti < 2; ++ti)
                    acc[oi][ti] = MFMA(a[oi][ks], bf[ti][ks], acc[oi][ti]);
        #pragma unroll
        for (int oi = 0; oi < 2; ++oi)
            #pragma unroll
            for (int ti = 0; ti < 2; ++ti) {
                const int t = t0 + ti * 16 + ln;
                #pragma unroll
                for (int r = 0; r < 4; ++r) {
                    const int d = dbase + oi * 16 + g * 4 + r;
                    vt[((size_t)combo * DHV + d) * TT + t] = (_Float16)acc[oi][ti][r];
                }
            }
    }
}

// ---------------------------------------------------------------------------
// Output projection, f16 MFMA (unchanged).
// ---------------------------------------------------------------------------
__global__ __launch_bounds__(256) void out_mfma(
    const _Float16* __restrict__ oc16, const _Float16* __restrict__ wout16,
    float* __restrict__ out)
{
    const int tid = threadIdx.x;
    const int wv = tid >> 6;
    const int lane = tid & 63;
    const int g = lane >> 4, ln = lane & 15;
    const int m0 = blockIdx.x * 64 + wv * 16;
    const int o0 = blockIdx.y * 32;
    f32x4 acc[2] = {};
    for (int k0 = 0; k0 < 1024; k0 += 32) {
        f16x8 a = *(const f16x8*)(oc16 + ((size_t)(m0 + ln)) * 1024 + k0 + g * 8);
        #pragma unroll
        for (int oi = 0; oi < 2; ++oi) {
            f16x8 bf = *(const f16x8*)(wout16 + ((size_t)(o0 + oi * 16 + ln)) * 1024 + k0 + g * 8);
            acc[oi] = MFMA(a, bf, acc[oi]);
        }
    }
    #pragma unroll
    for (int oi = 0; oi < 2; ++oi)
        #pragma unroll
        for (int r = 0; r < 4; ++r)
            out[((size_t)(m0 + g * 4 + r)) * CIN + o0 + oi * 16 + ln] = acc[oi][r];
}

// ---------------------------------------------------------------------------
// f16 MFMA flash attention: LDS-staged, FULLY double-buffered K AND V ->
// ONE barrier per 64-key tile. Iter n: stage K(n+1),V(n+1) -> buf[cur^1]
// (fully consumed & barrier-protected at iter n-1), compute QK^T/softmax/PV
// entirely from buf[cur], then __syncthreads() (drains vmcnt).
// Block = 4 waves x 16 q-rows; grid 36x32=1152, XCD-affine combo mapping.
// LDS XOR-swizzle on source address at staging + on ds_read (m173/m201).
// ---------------------------------------------------------------------------
__global__ __launch_bounds__(256, 3) void attn_mfma(
    const _Float16* __restrict__ qh, const _Float16* __restrict__ kh,
    const _Float16* __restrict__ vt, _Float16* __restrict__ oc16)
{
    __shared__ __align__(16) _Float16 Kls[2][4096];   // [64 rows][64 f16] swizzled
    __shared__ __align__(16) _Float16 Vls[2][4096];   // [64 d][64 k] swizzled
    __shared__ __align__(16) _Float16 Plds[4][16][88];

    const int tid = threadIdx.x;
    const int wv = tid >> 6;
    const int lane = tid & 63;
    const int g = lane >> 4, ln = lane & 15;
    const int bid = blockIdx.x;
    const int xcd = bid & 7, slot = bid >> 3;          // 1152 = 8 x 144
    const int combo = (xcd << 2) | (slot / 36);
    const int q0 = (slot % 36) * 64 + wv * 16;
    const _Float16* Q = qh + (size_t)combo * TT * DHV;
    const _Float16* K = kh + (size_t)combo * TT * DHV;
    const _Float16* V = vt + (size_t)combo * DHV * TT;

    // staging geometry: wave stages rows [wv*16, wv*16+16) of the 64-row tile
    const int srow = wv * 16 + (lane >> 3);
    const int scol = ((lane & 7) ^ ((lane >> 3) & 7)) * 8;   // source-side swizzle
    const int sw = (ln & 7) << 3;                            // read-side XOR (elems)

    f16x8 bq[2];
    #pragma unroll
    for (int k0 = 0; k0 < 2; ++k0)
        bq[k0] = *(const f16x8*)(Q + ((size_t)(q0 + ln)) * DHV + k0 * 32 + g * 8);

    f32x4 O[4] = {};
    float mrun = -1e30f, lrun = 0.f;

    // prologue: stage K(0), V(0) -> buf 0
    #pragma unroll
    for (int j = 0; j < 2; ++j)
        __builtin_amdgcn_global_load_lds(
            (gu32*)(K + (size_t)(srow + j * 8) * DHV + scol),
            (lu32*)&Kls[0][(wv * 2 + j) * 512], 16, 0, 0);
    #pragma unroll
    for (int j = 0; j < 2; ++j)
        __builtin_amdgcn_global_load_lds(
            (gu32*)(V + (size_t)(srow + j * 8) * TT + 0 + scol),
            (lu32*)&Vls[0][(wv * 2 + j) * 512], 16, 0, 0);
    __syncthreads();

    int cur = 0;
    for (int it = 0; it < TT / 64; ++it) {
        const int kn = (it + 1 < TT / 64) ? (it + 1) * 64 : 0;  // last-iter dummy

        // ---- stage K(next), V(next) -> buf[cur^1] (fire-and-forget) ----
        #pragma unroll
        for (int j = 0; j < 2; ++j)
            __builtin_amdgcn_global_load_lds(
                (gu32*)(K + (size_t)(kn + srow + j * 8) * DHV + scol),
                (lu32*)&Kls[cur ^ 1][(wv * 2 + j) * 512], 16, 0, 0);
        #pragma unroll
        for (int j = 0; j < 2; ++j)
            __builtin_amdgcn_global_load_lds(
                (gu32*)(V + (size_t)(srow + j * 8) * TT + kn + scol),
                (lu32*)&Vls[cur ^ 1][(wv * 2 + j) * 512], 16, 0, 0);

        // ---- QK^T (swapped) from Kls[cur] ----
        f32x4 S[4] = {};
        __builtin_amdgcn_s_setprio(1);
        #pragma unroll
        for (int m = 0; m < 4; ++m) {
            f16x8 ak0 = *(const f16x8*)&Kls[cur][(((m * 16 + ln) * 64) + 0 * 32 + g * 8) ^ sw];
            f16x8 ak1 = *(const f16x8*)&Kls[cur][(((m * 16 + ln) * 64) + 1 * 32 + g * 8) ^ sw];
            S[m] = MFMA(ak0, bq[0], S[m]);
            S[m] = MFMA(ak1, bq[1], S[m]);
        }
        __builtin_amdgcn_s_setprio(0);

        // ---- online softmax (rows lane-local; exp2 domain; tree) ----
        {
            float a0 = fmaxf(fmaxf(S[0][0], S[0][1]), fmaxf(S[0][2], S[0][3]));
            float a1 = fmaxf(fmaxf(S[1][0], S[1][1]), fmaxf(S[1][2], S[1][3]));
            float a2 = fmaxf(fmaxf(S[2][0], S[2][1]), fmaxf(S[2][2], S[2][3]));
            float a3 = fmaxf(fmaxf(S[3][0], S[3][1]), fmaxf(S[3][2], S[3][3]));
            float mx = fmaxf(fmaxf(a0, a1), fmaxf(a2, a3));
            mx = fmaxf(mx, __shfl_xor(mx, 16));
            mx = fmaxf(mx, __shfl_xor(mx, 32));
            const float mnew = fmaxf(mrun, mx);
            const float corr = exp2f(mrun - mnew);
            float psm[4];
            #pragma unroll
            for (int m = 0; m < 4; ++m) {
                #pragma unroll
                for (int r = 0; r < 4; ++r)
                    S[m][r] = exp2f(S[m][r] - mnew);
                psm[m] = (S[m][0] + S[m][1]) + (S[m][2] + S[m][3]);
            }
            float ps = (psm[0] + psm[1]) + (psm[2] + psm[3]);
            ps += __shfl_xor(ps, 16);
            ps += __shfl_xor(ps, 32);
            lrun = lrun * corr + ps;
            mrun = mnew;
            #pragma unroll
            for (int m = 0; m < 4; ++m) O[m] *= corr;
            #pragma unroll
            for (int m = 0; m < 4; ++m) {
                uint2 u;
                u.x = pk2(S[m][0], S[m][1]);
                u.y = pk2(S[m][2], S[m][3]);
                *(uint2*)&Plds[wv][ln][m * 16 + g * 4] = u;
            }
        }

        // ---- PV (swapped) from Vls[cur] ----
        f16x8 bp[2];
        #pragma unroll
        for (int kc0 = 0; kc0 < 2; ++kc0)
            bp[kc0] = *(const f16x8*)&Plds[wv][ln][kc0 * 32 + g * 8];
        __builtin_amdgcn_s_setprio(1);
        #pragma unroll
        for (int m = 0; m < 4; ++m) {
            f16x8 av0 = *(const f16x8*)&Vls[cur][(((m * 16 + ln) * 64) + 0 * 32 + g * 8) ^ sw];
            f16x8 av1 = *(const f16x8*)&Vls[cur][(((m * 16 + ln) * 64) + 1 * 32 + g * 8) ^ sw];
            O[m] = MFMA(av0, bp[0], O[m]);
            O[m] = MFMA(av1, bp[1], O[m]);
        }
        __builtin_amdgcn_s_setprio(0);

        // ONE barrier: drains this wave's stages (vmcnt) + all waves done
        // reading buf[cur] -> buf[cur] safe to overwrite next iter.
        __syncthreads();
        cur ^= 1;
    }

    // ---- epilogue: wave-private 16 q-rows ----
    const int s_ = combo >> 3, b_ = (combo >> 2) & 1, h_ = combo & 3;
    const float inv = 1.f / lrun;
    const int tok = q0 + ln;
    #pragma unroll
    for (int m = 0; m < 4; ++m) {
        uint2 u;
        u.x = pk2(O[m][0] * inv, O[m][1] * inv);
        u.y = pk2(O[m][2] * inv, O[m][3] * inv);
        *(uint2*)&oc16[((size_t)(b_ * TT + tok)) * 1024 + s_ * 256 + h_ * 64 + m * 16 + g * 4] = u;
    }
}

// ---------------------------------------------------------------------------
extern "C" void kernel_launch(void* const* d_in, const int* in_sizes, int n_in,
                              void* d_out, int out_size, void* d_ws, size_t ws_size,
                              hipStream_t stream)
{
    const float* x    = (const float*)d_in[0];
    const float* wci  = (const float*)d_in[1];
    const float* b1g  = (const float*)d_in[2];
    const float* b1b  = (const float*)d_in[3];
    const float* b1m  = (const float*)d_in[4];
    const float* b1v  = (const float*)d_in[5];
    const float* dww  = (const float*)d_in[6];
    const float* pww  = (const float*)d_in[7];
    const float* b2g  = (const float*)d_in[8];
    const float* b2b  = (const float*)d_in[9];
    const float* b2m  = (const float*)d_in[10];
    const float* b2v  = (const float*)d_in[11];
    const float* Wq   = (const float*)d_in[12];
    const float* Wk   = (const float*)d_in[13];
    const float* Wv   = (const float*)d_in[14];
    const float* Wout = (const float*)d_in[15];

    char* wsb = (char*)d_ws;
    float*     ident = (float*)(wsb + WSB_IDENT);
    _Float16*  rt16  = (_Float16*)(wsb + WSB_RT16);
    float*     dwt   = (float*)(wsb + WSB_DWT);
    float*     ysch  = (float*)(wsb + WSB_YS);
    _Float16*  qh    = (_Float16*)(wsb + WSB_QH);
    _Float16*  khp   = (_Float16*)(wsb + WSB_KH);
    _Float16*  vtp   = (_Float16*)(wsb + WSB_VT);
    _Float16*  oc16  = (_Float16*)(wsb + WSB_OC16);
    _Float16*  w16   = (_Float16*)(wsb + WSB_W16);
    _Float16*  x16   = (_Float16*)(wsb + WSB_X16);
    float*     outp  = (float*)d_out;

    // 0) f32->f16: wq, wk, wv, wout, wci, x (194560 units = 760 x 256)
    wcvt<<<dim3(760), 256, 0, stream>>>(Wq, Wk, Wv, Wout, wci, x, w16, x16);

    // 1) conv_in (1x1) + BN1, f16 MFMA -> identity f32 + rt16 scale0
    cin_mfma<<<dim3(36, 4), 256, 0, stream>>>(
        x16, w16 + 311296, b1g, b1b, b1m, b1v, ident, rt16);

    // 2) Res2Net chain: dw3x3 -> pw 1x1 + BN2 -> rt16[s] + ys_ch, scales 1..3
    for (int s = 1; s <= 3; ++s) {
        const float* yp = (s == 1) ? nullptr : (ysch + (size_t)(s - 2) * BB * C4 * TT);
        dw3x3<<<dim3(BB * C4 * TT / 256), 256, 0, stream>>>(ident, yp, dww, dwt, s);
        pw_gemm<<<dim3(BB * TT / 64), 256, 0, stream>>>(
            dwt, pww, (float*)rt16, ysch, b2g, b2b, b2m, b2v, s);
    }

    // 3) q/k/v projections, f16 MFMA -> qh (log2e-scaled), kh, vt (V^T)
    qkv_mfma<<<dim3(144, 8, 3), 256, 0, stream>>>(rt16, w16, qh, khp, vtp);

    // 4) f16 MFMA flash attention (dbuf K+V, 1 barrier/iter) -> oc16 f16
    attn_mfma<<<dim3(36 * 32), 256, 0, stream>>>(qh, khp, vtp, oc16);

    // 5) output projection, f16 MFMA -> d_out f32
    out_mfma<<<dim3(72, 8), 256, 0, stream>>>(oc16, w16 + 49152, outp);
}